// Round 2
// baseline (6683.292 us; speedup 1.0000x reference)
//
#include <hip/hip_runtime.h>
#include <math.h>

// Problem constants (fixed by the reference)
#define Nn 50000
#define Ee 400000
#define Gg 2000
#define NPGc 25
#define Hc 128
#define Lc 5

// ------------------------------------------------------------------
// Graph preprocessing kernels (run once per call, shared by branches)
// ------------------------------------------------------------------
__global__ void deg_kernel(const int* __restrict__ dst, int* __restrict__ deg, int E){
  int i = blockIdx.x * blockDim.x + threadIdx.x;
  if (i < E) atomicAdd(&deg[dst[i]], 1);
}

// single-block exclusive scan over N=50000 (trivial cost)
__global__ void scan_kernel(const int* __restrict__ deg, int* __restrict__ rowstart, int n){
  __shared__ int tmp[1024];
  int tid = threadIdx.x;
  if (tid == 0) rowstart[0] = 0;
  int base = 0;
  for (int start = 0; start < n; start += 1024){
    int i = start + tid;
    int v = (i < n) ? deg[i] : 0;
    tmp[tid] = v;
    __syncthreads();
    for (int off = 1; off < 1024; off <<= 1){
      int add = (tid >= off) ? tmp[tid - off] : 0;
      __syncthreads();
      tmp[tid] += add;
      __syncthreads();
    }
    if (i < n) rowstart[i + 1] = base + tmp[tid];
    base += tmp[1023];
    __syncthreads();
  }
}

__global__ void copy_int_kernel(const int* __restrict__ a, int* __restrict__ b, int n){
  int i = blockIdx.x * blockDim.x + threadIdx.x;
  if (i < n) b[i] = a[i];
}

// sort edges by dst; store src and the 0..124 edge-feature code
__global__ void scatter_kernel(const int* __restrict__ src, const int* __restrict__ dst,
                               const int* __restrict__ ef, int* cursor,
                               int* __restrict__ src_srt, int* __restrict__ code_srt, int E){
  int i = blockIdx.x * blockDim.x + threadIdx.x;
  if (i >= E) return;
  int p = atomicAdd(&cursor[dst[i]], 1);
  src_srt[p] = src[i];
  code_srt[p] = ef[i * 3 + 0] * 25 + ef[i * 3 + 1] * 5 + ef[i * 3 + 2];
}

__global__ void ampatt_kernel(const int* __restrict__ deg, float* __restrict__ amp,
                              float* __restrict__ att, int n){
  int i = blockIdx.x * blockDim.x + threadIdx.x;
  if (i >= n) return;
  float d = (float)deg[i];
  float ld = logf(d + 1.0f);                 // amp = log_deg / D_LOG, D_LOG=1
  amp[i] = ld;
  att[i] = (deg[i] > 0) ? (1.0f / ld) : 0.0f;
}

// ------------------------------------------------------------------
// Node embedding: h[n][c] = sum_f aemb[nf[n][f] + 16*f][c]
// ------------------------------------------------------------------
__global__ void embed_node_kernel(const int* __restrict__ nf, const float* __restrict__ aemb,
                                  float* __restrict__ h){
  int idx = blockIdx.x * blockDim.x + threadIdx.x;
  if (idx >= Nn * Hc) return;
  int n = idx >> 7, c = idx & 127;
  float s = 0.f;
#pragma unroll
  for (int f = 0; f < 9; f++){
    int row = nf[n * 9 + f] + 16 * f;
    s += aemb[row * Hc + c];
  }
  h[idx] = s;
}

// ------------------------------------------------------------------
// bsum[code][c] = bemb[e0][c] + bemb[5+e1][c] + bemb[10+e2][c]
// code = e0*25 + e1*5 + e2  (only 125 distinct edge embeddings exist)
// ------------------------------------------------------------------
__global__ void bsum_kernel(const float* __restrict__ bemb, float* __restrict__ bsum){
  int idx = blockIdx.x * blockDim.x + threadIdx.x;
  if (idx >= 125 * Hc) return;
  int code = idx >> 7, c = idx & 127;
  int e0 = code / 25, e1 = (code / 5) % 5, e2 = code % 5;
  bsum[idx] = bemb[e0 * Hc + c] + bemb[(5 + e1) * Hc + c] + bemb[(10 + e2) * Hc + c];
}

// ------------------------------------------------------------------
// PNA aggregation: z_k = hs[src_k] + hd[n] + ezt[code_k]
// stats out: mean | max | min | std (zeros for deg==0 nodes)
// Processes nodes [n0, n0+gridDim.x); agg buffer is chunk-local.
// ------------------------------------------------------------------
__global__ void agg_kernel(const float* __restrict__ hs, const float* __restrict__ hd,
                           const float* __restrict__ ezt, const int* __restrict__ src_srt,
                           const int* __restrict__ code_srt, const int* __restrict__ rowstart,
                           float* __restrict__ agg, int n0){
  int n = n0 + blockIdx.x;
  int c = threadIdx.x;
  int s0 = rowstart[n], s1 = rowstart[n + 1];
  float* out = agg + (size_t)blockIdx.x * 512;
  if (s1 == s0){
    out[c] = 0.f; out[128 + c] = 0.f; out[256 + c] = 0.f; out[384 + c] = 0.f;
    return;
  }
  float hdc = hd[(size_t)n * Hc + c];
  float sum = 0.f, sum2 = 0.f, mx = -3.402823466e38f, mn = 3.402823466e38f;
  for (int k = s0; k < s1; k++){
    int sidx = src_srt[k];
    float z = hs[(size_t)sidx * Hc + c] + hdc + ezt[(size_t)code_srt[k] * Hc + c];
    sum += z; sum2 += z * z;
    mx = fmaxf(mx, z); mn = fminf(mn, z);
  }
  float d  = (float)(s1 - s0);
  float m  = sum / d;
  float ms = sum2 / d;
  float var = ms - m * m;
  var = var > 0.f ? var : 0.f;            // jax.nn.relu
  out[c]       = m;
  out[128 + c] = mx;
  out[256 + c] = mn;
  out[384 + c] = sqrtf(var + 1e-5f);
}

// ------------------------------------------------------------------
// Graph readout: [min | max | mean] over the 25 nodes of each graph
// ------------------------------------------------------------------
__global__ void readout_kernel(const float* __restrict__ h, float* __restrict__ r){
  int g = blockIdx.x, c = threadIdx.x;
  float mn = 3.402823466e38f, mx = -3.402823466e38f, s = 0.f;
  const float* hp = h + (size_t)g * NPGc * Hc + c;
#pragma unroll
  for (int i = 0; i < NPGc; i++){
    float v = hp[i * Hc];
    mn = fminf(mn, v); mx = fmaxf(mx, v); s += v;
  }
  r[(size_t)g * 384 + c]       = mn;
  r[(size_t)g * 384 + 128 + c] = mx;
  r[(size_t)g * 384 + 256 + c] = s * (1.0f / NPGc);
}

__global__ void concat_kernel(const float* __restrict__ r2, const float* __restrict__ lat3,
                              float* __restrict__ x){
  int idx = blockIdx.x * blockDim.x + threadIdx.x;
  if (idx >= Gg * 640) return;
  int g = idx / 640, c = idx % 640;
  x[idx] = (c < 384) ? r2[g * 384 + c] : lat3[g * 256 + (c - 384)];
}

// ------------------------------------------------------------------
// fp32 tiled GEMM: C[M,NC] = Asrc[M,K] @ B[K,NC] (+bias)(+resid)(relu?)
//   MODE 0: A from global row-major (lda=K)
//   MODE 2: A row = [h(128) | agg(512) | agg*amp(512) | agg*att(512)]; K=1664
// 64x64 block tile, 256 threads, 4x4 microtile, K-chunk 16, float4 LDS reads.
// ------------------------------------------------------------------
template<int MODE, bool RELU>
__global__ __launch_bounds__(256)
void gemm_kernel(const float* __restrict__ A, const float* __restrict__ B,
                 const float* __restrict__ bias, const float* __restrict__ resid,
                 float* __restrict__ C, int M, int K, int NC,
                 const float* __restrict__ agg, const float* __restrict__ amp,
                 const float* __restrict__ att)
{
  __shared__ __align__(16) float As[16][68];   // [kk][row]
  __shared__ __align__(16) float Bs[16][68];   // [kk][col]

  int tid  = threadIdx.x;
  int row0 = blockIdx.y * 64;
  int col0 = blockIdx.x * 64;

  float acc[4][4];
#pragma unroll
  for (int i = 0; i < 4; i++)
#pragma unroll
    for (int j = 0; j < 4; j++) acc[i][j] = 0.f;

  int tm = tid >> 4;       // 0..15 -> rows tm*4..tm*4+3
  int tn = tid & 15;       // 0..15 -> cols tn*4..tn*4+3
  int kk_a = tid & 15;     // A staging: k within chunk
  int r_a  = tid >> 4;     // A staging: row base, step 16
  int c_b  = tid & 63;     // B staging: col
  int k_b  = tid >> 6;     // B staging: k base, step 4

  for (int k0 = 0; k0 < K; k0 += 16){
    // stage A (transposed: As[kk][row])
#pragma unroll
    for (int i = 0; i < 4; i++){
      int rr = r_a + i * 16;
      int grow = row0 + rr;
      int gk = k0 + kk_a;
      float v = 0.f;
      if (grow < M){
        if (MODE == 0){
          v = A[(size_t)grow * K + gk];
        } else {
          if      (gk <  128) v = A[(size_t)grow * 128 + gk];
          else if (gk <  640) v = agg[(size_t)grow * 512 + (gk - 128)];
          else if (gk < 1152) v = agg[(size_t)grow * 512 + (gk - 640)] * amp[grow];
          else                v = agg[(size_t)grow * 512 + (gk - 1152)] * att[grow];
        }
      }
      As[kk_a][rr] = v;
    }
    // stage B
#pragma unroll
    for (int i = 0; i < 4; i++){
      int kr = k_b + i * 4;
      int gk = k0 + kr;
      int gc = col0 + c_b;
      Bs[kr][c_b] = (gc < NC) ? B[(size_t)gk * NC + gc] : 0.f;
    }
    __syncthreads();
#pragma unroll
    for (int kk = 0; kk < 16; kk++){
      float4 a = *(const float4*)&As[kk][tm * 4];
      float4 b = *(const float4*)&Bs[kk][tn * 4];
      acc[0][0] += a.x * b.x; acc[0][1] += a.x * b.y; acc[0][2] += a.x * b.z; acc[0][3] += a.x * b.w;
      acc[1][0] += a.y * b.x; acc[1][1] += a.y * b.y; acc[1][2] += a.y * b.z; acc[1][3] += a.y * b.w;
      acc[2][0] += a.z * b.x; acc[2][1] += a.z * b.y; acc[2][2] += a.z * b.z; acc[2][3] += a.z * b.w;
      acc[3][0] += a.w * b.x; acc[3][1] += a.w * b.y; acc[3][2] += a.w * b.z; acc[3][3] += a.w * b.w;
    }
    __syncthreads();
  }

#pragma unroll
  for (int i = 0; i < 4; i++){
    int r = row0 + tm * 4 + i;
    if (r >= M) continue;
#pragma unroll
    for (int j = 0; j < 4; j++){
      int c = col0 + tn * 4 + j;
      if (c >= NC) continue;
      float v = acc[i][j];
      if (bias)  v += bias[c];
      if (resid) v += resid[(size_t)r * NC + c];
      if (RELU)  v = fmaxf(v, 0.f);
      C[(size_t)r * NC + c] = v;
    }
  }
}

// ------------------------------------------------------------------
extern "C" void kernel_launch(void* const* d_in, const int* in_sizes, int n_in,
                              void* d_out, int out_size, void* d_ws, size_t ws_size,
                              hipStream_t stream)
{
  // inputs in setup_inputs() dict order
  const int*   node_feat = (const int*)  d_in[0];   // [N,9]
  const int*   edge_feat = (const int*)  d_in[1];   // [E,3]
  const int*   src       = (const int*)  d_in[2];
  const int*   dst       = (const int*)  d_in[3];
  /* graph_id d_in[4] derived: arange(N)//25 */
  const float* aemb_f  = (const float*) d_in[5];
  const float* bemb_f  = (const float*) d_in[6];
  const float* w_pre_f = (const float*) d_in[7];
  const float* b_pre_f = (const float*) d_in[8];
  const float* w_post_f= (const float*) d_in[9];
  const float* b_post_f= (const float*) d_in[10];
  const float* w_out3  = (const float*) d_in[11];
  const float* b_out3  = (const float*) d_in[12];
  const float* aemb    = (const float*) d_in[13];
  const float* bemb    = (const float*) d_in[14];
  const float* w_pre   = (const float*) d_in[15];
  const float* b_pre   = (const float*) d_in[16];
  const float* w_post  = (const float*) d_in[17];
  const float* b_post  = (const float*) d_in[18];
  const float* w1      = (const float*) d_in[19];
  const float* b1      = (const float*) d_in[20];
  const float* w2      = (const float*) d_in[21];
  const float* b2      = (const float*) d_in[22];
  float* out = (float*)d_out;

  // ---- workspace carve: fixed buffers first (~121 MB), agg takes the rest ----
  char* w = (char*)d_ws;
  auto carve = [&](size_t bytes) -> void* {
    void* p = (void*)w;
    w += (bytes + 255) & ~(size_t)255;
    return p;
  };
  float* h_a   = (float*)carve((size_t)Nn * Hc * 4);
  float* h_b   = (float*)carve((size_t)Nn * Hc * 4);
  float* hs    = (float*)carve((size_t)Nn * Hc * 4);
  float* hd    = (float*)carve((size_t)Nn * Hc * 4);
  float* bsum  = (float*)carve((size_t)125 * Hc * 4);
  float* ezt   = (float*)carve((size_t)125 * Hc * 4);
  float* amp   = (float*)carve((size_t)Nn * 4);
  float* att   = (float*)carve((size_t)Nn * 4);
  float* r3    = (float*)carve((size_t)Gg * 384 * 4);
  float* r2    = (float*)carve((size_t)Gg * 384 * 4);
  float* lat3  = (float*)carve((size_t)Gg * 256 * 4);
  float* xcat  = (float*)carve((size_t)Gg * 640 * 4);
  float* h1buf = (float*)carve((size_t)Gg * Hc * 4);
  int* deg      = (int*)carve((size_t)Nn * 4);
  int* rowstart = (int*)carve((size_t)(Nn + 1) * 4);
  int* cursor   = (int*)carve((size_t)Nn * 4);
  int* src_srt  = (int*)carve((size_t)Ee * 4);
  int* code_srt = (int*)carve((size_t)Ee * 4);

  size_t fixed_bytes = (size_t)(w - (char*)d_ws);
  size_t avail = (ws_size > fixed_bytes) ? (ws_size - fixed_bytes) : 0;
  long max_rows = (long)(avail / (512 * 4));
  int chunk = (max_rows >= Nn) ? Nn : (int)(max_rows & ~63L);
  if (chunk < 64) chunk = 64;   // ws too small to matter anyway
  float* agg = (float*)w;       // chunk * 512 floats

  // ---- graph preprocessing (shared by both branches) ----
  hipMemsetAsync(deg, 0, (size_t)Nn * 4, stream);
  deg_kernel<<<(Ee + 255) / 256, 256, 0, stream>>>(dst, deg, Ee);
  scan_kernel<<<1, 1024, 0, stream>>>(deg, rowstart, Nn);
  copy_int_kernel<<<(Nn + 255) / 256, 256, 0, stream>>>(rowstart, cursor, Nn);
  scatter_kernel<<<(Ee + 255) / 256, 256, 0, stream>>>(src, dst, edge_feat, cursor,
                                                       src_srt, code_srt, Ee);
  ampatt_kernel<<<(Nn + 255) / 256, 256, 0, stream>>>(deg, amp, att, Nn);

  // ---- one PNA branch ----
  auto run_branch = [&](const float* aemb_p, const float* bemb_p,
                        const float* w_pre_p, const float* b_pre_p,
                        const float* w_post_p, const float* b_post_p,
                        float* r_out)
  {
    float* h_cur = h_a;
    float* h_nxt = h_b;
    embed_node_kernel<<<(Nn * Hc + 255) / 256, 256, 0, stream>>>(node_feat, aemb_p, h_cur);
    bsum_kernel<<<(125 * Hc + 255) / 256, 256, 0, stream>>>(bemb_p, bsum);
    for (int l = 0; l < Lc; l++){
      const float* wl = w_pre_p + (size_t)l * 384 * 128;
      // hs = h @ W_src ; hd = h @ W_dst
      gemm_kernel<0, false><<<dim3(2, (Nn + 63) / 64), 256, 0, stream>>>(
          h_cur, wl, nullptr, nullptr, hs, Nn, 128, 128, nullptr, nullptr, nullptr);
      gemm_kernel<0, false><<<dim3(2, (Nn + 63) / 64), 256, 0, stream>>>(
          h_cur, wl + 128 * 128, nullptr, nullptr, hd, Nn, 128, 128, nullptr, nullptr, nullptr);
      // ezt = bsum @ W_e + b_pre  (125 distinct edge embeddings)
      gemm_kernel<0, false><<<dim3(2, 2), 256, 0, stream>>>(
          bsum, wl + 256 * 128, b_pre_p + (size_t)l * 128, nullptr, ezt, 125, 128, 128,
          nullptr, nullptr, nullptr);
      // chunked: agg stats then post GEMM per node-chunk
      for (int n0 = 0; n0 < Nn; n0 += chunk){
        int rows = (Nn - n0 < chunk) ? (Nn - n0) : chunk;
        agg_kernel<<<rows, 128, 0, stream>>>(hs, hd, ezt, src_srt, code_srt,
                                             rowstart, agg, n0);
        gemm_kernel<2, false><<<dim3(2, (rows + 63) / 64), 256, 0, stream>>>(
            h_cur + (size_t)n0 * Hc, w_post_p + (size_t)l * 1664 * 128,
            b_post_p + (size_t)l * 128, h_cur + (size_t)n0 * Hc,
            h_nxt + (size_t)n0 * Hc, rows, 1664, 128,
            agg, amp + n0, att + n0);
      }
      float* t = h_cur; h_cur = h_nxt; h_nxt = t;
    }
    readout_kernel<<<Gg, 128, 0, stream>>>(h_cur, r_out);
  };

  // frozen 3D branch -> latent3d
  run_branch(aemb_f, bemb_f, w_pre_f, b_pre_f, w_post_f, b_post_f, r3);
  gemm_kernel<0, false><<<dim3(4, (Gg + 63) / 64), 256, 0, stream>>>(
      r3, w_out3, b_out3, nullptr, lat3, Gg, 384, 256, nullptr, nullptr, nullptr);

  // trainable 2D branch
  run_branch(aemb, bemb, w_pre, b_pre, w_post, b_post, r2);

  // head: x=[r2|latent3d]; h1=relu(x@w1+b1); out=h1@w2+b2
  concat_kernel<<<(Gg * 640 + 255) / 256, 256, 0, stream>>>(r2, lat3, xcat);
  gemm_kernel<0, true><<<dim3(2, (Gg + 63) / 64), 256, 0, stream>>>(
      xcat, w1, b1, nullptr, h1buf, Gg, 640, 128, nullptr, nullptr, nullptr);
  gemm_kernel<0, false><<<dim3(2, (Gg + 63) / 64), 256, 0, stream>>>(
      h1buf, w2, b2, nullptr, out, Gg, 128, 128, nullptr, nullptr, nullptr);
}

// Round 3
// 2849.901 us; speedup vs baseline: 2.3451x; 2.3451x over previous
//
#include <hip/hip_runtime.h>
#include <hip/hip_bf16.h>
#include <math.h>

// Problem constants (fixed by the reference)
#define Nn 50000
#define Ee 400000
#define Gg 2000
#define NPGc 25
#define Hc 128
#define Lc 5

typedef __attribute__((ext_vector_type(8))) short short8;   // 8 bf16 = 4 VGPRs
typedef __attribute__((ext_vector_type(4))) float fx4;      // MFMA accumulator

// round-to-nearest-even fp32 -> bf16 (as raw short)
__device__ inline short bf16r(float x){
  unsigned u = __float_as_uint(x);
  unsigned r = (u + 0x7fffu + ((u >> 16) & 1u)) >> 16;
  return (short)r;
}

// ------------------------------------------------------------------
// Graph preprocessing (once per call, shared by branches)
// ------------------------------------------------------------------
__global__ void deg_kernel(const int* __restrict__ dst, int* __restrict__ deg, int E){
  int i = blockIdx.x * blockDim.x + threadIdx.x;
  if (i < E) atomicAdd(&deg[dst[i]], 1);
}

__global__ void scan_kernel(const int* __restrict__ deg, int* __restrict__ rowstart, int n){
  __shared__ int tmp[1024];
  int tid = threadIdx.x;
  if (tid == 0) rowstart[0] = 0;
  int base = 0;
  for (int start = 0; start < n; start += 1024){
    int i = start + tid;
    int v = (i < n) ? deg[i] : 0;
    tmp[tid] = v;
    __syncthreads();
    for (int off = 1; off < 1024; off <<= 1){
      int add = (tid >= off) ? tmp[tid - off] : 0;
      __syncthreads();
      tmp[tid] += add;
      __syncthreads();
    }
    if (i < n) rowstart[i + 1] = base + tmp[tid];
    base += tmp[1023];
    __syncthreads();
  }
}

__global__ void copy_int_kernel(const int* __restrict__ a, int* __restrict__ b, int n){
  int i = blockIdx.x * blockDim.x + threadIdx.x;
  if (i < n) b[i] = a[i];
}

__global__ void scatter_kernel(const int* __restrict__ src, const int* __restrict__ dst,
                               const int* __restrict__ ef, int* cursor,
                               int* __restrict__ src_srt, int* __restrict__ code_srt, int E){
  int i = blockIdx.x * blockDim.x + threadIdx.x;
  if (i >= E) return;
  int p = atomicAdd(&cursor[dst[i]], 1);
  src_srt[p] = src[i];
  code_srt[p] = ef[i * 3 + 0] * 25 + ef[i * 3 + 1] * 5 + ef[i * 3 + 2];
}

__global__ void ampatt_kernel(const int* __restrict__ deg, float* __restrict__ amp,
                              float* __restrict__ att, int n){
  int i = blockIdx.x * blockDim.x + threadIdx.x;
  if (i >= n) return;
  float d = (float)deg[i];
  float ld = logf(d + 1.0f);
  amp[i] = ld;
  att[i] = (deg[i] > 0) ? (1.0f / ld) : 0.0f;
}

// ------------------------------------------------------------------
// Node embedding: h fp32 + bf16 shadow
// ------------------------------------------------------------------
__global__ void embed_node_kernel(const int* __restrict__ nf, const float* __restrict__ aemb,
                                  float* __restrict__ h, short* __restrict__ h16){
  int idx = blockIdx.x * blockDim.x + threadIdx.x;
  if (idx >= Nn * Hc) return;
  int n = idx >> 7, c = idx & 127;
  float s = 0.f;
#pragma unroll
  for (int f = 0; f < 9; f++){
    int row = nf[n * 9 + f] + 16 * f;
    s += aemb[row * Hc + c];
  }
  h[idx] = s;
  h16[idx] = bf16r(s);
}

// bsum[code][c]: 125 distinct edge embeddings
__global__ void bsum_kernel(const float* __restrict__ bemb, float* __restrict__ bsum){
  int idx = blockIdx.x * blockDim.x + threadIdx.x;
  if (idx >= 125 * Hc) return;
  int code = idx >> 7, c = idx & 127;
  int e0 = code / 25, e1 = (code / 5) % 5, e2 = code % 5;
  bsum[idx] = bemb[e0 * Hc + c] + bemb[(5 + e1) * Hc + c] + bemb[(10 + e2) * Hc + c];
}

// ------------------------------------------------------------------
// per-layer weight converts (tiny)
// w_post [1664][128] fp32 -> Bt [128][1664] bf16
__global__ void conv_wpost_kernel(const float* __restrict__ w, short* __restrict__ Bt){
  int idx = blockIdx.x * blockDim.x + threadIdx.x;
  if (idx >= 1664 * 128) return;
  int k = idx >> 7, c = idx & 127;
  Bt[(size_t)c * 1664 + k] = bf16r(w[idx]);
}
// w_pre rows 0..255 ([W_src; W_dst]) -> Btp [256 cols][128 k] bf16
__global__ void conv_wpre_kernel(const float* __restrict__ wl, short* __restrict__ Btp){
  int idx = blockIdx.x * blockDim.x + threadIdx.x;
  if (idx >= 256 * 128) return;
  int col = idx >> 7, k = idx & 127;
  float v = (col < 128) ? wl[k * 128 + col] : wl[(128 + k) * 128 + (col - 128)];
  Btp[col * 128 + k] = bf16r(v);
}

// ------------------------------------------------------------------
// PNA aggregation: z_k = hs[src_k] + hd[n] + ezt[code_k]
// hsd is [N][256] fp32: cols 0..127 = hs, 128..255 = hd
// ------------------------------------------------------------------
__global__ void agg_kernel(const float* __restrict__ hsd, const float* __restrict__ ezt,
                           const int* __restrict__ src_srt, const int* __restrict__ code_srt,
                           const int* __restrict__ rowstart,
                           float* __restrict__ agg, int n0){
  int n = n0 + blockIdx.x;
  int c = threadIdx.x;
  int s0 = rowstart[n], s1 = rowstart[n + 1];
  float* out = agg + (size_t)blockIdx.x * 512;
  if (s1 == s0){
    out[c] = 0.f; out[128 + c] = 0.f; out[256 + c] = 0.f; out[384 + c] = 0.f;
    return;
  }
  float hdc = hsd[(size_t)n * 256 + 128 + c];
  float sum = 0.f, sum2 = 0.f, mx = -3.402823466e38f, mn = 3.402823466e38f;
  for (int k = s0; k < s1; k++){
    int sidx = src_srt[k];
    float z = hsd[(size_t)sidx * 256 + c] + hdc + ezt[(size_t)code_srt[k] * Hc + c];
    sum += z; sum2 += z * z;
    mx = fmaxf(mx, z); mn = fminf(mn, z);
  }
  float d  = (float)(s1 - s0);
  float m  = sum / d;
  float ms = sum2 / d;
  float var = ms - m * m;
  var = var > 0.f ? var : 0.f;
  out[c]       = m;
  out[128 + c] = mx;
  out[256 + c] = mn;
  out[384 + c] = sqrtf(var + 1e-5f);
}

// ------------------------------------------------------------------
// Graph readout: [min | max | mean]
// ------------------------------------------------------------------
__global__ void readout_kernel(const float* __restrict__ h, float* __restrict__ r){
  int g = blockIdx.x, c = threadIdx.x;
  float mn = 3.402823466e38f, mx = -3.402823466e38f, s = 0.f;
  const float* hp = h + (size_t)g * NPGc * Hc + c;
#pragma unroll
  for (int i = 0; i < NPGc; i++){
    float v = hp[i * Hc];
    mn = fminf(mn, v); mx = fmaxf(mx, v); s += v;
  }
  r[(size_t)g * 384 + c]       = mn;
  r[(size_t)g * 384 + 128 + c] = mx;
  r[(size_t)g * 384 + 256 + c] = s * (1.0f / NPGc);
}

__global__ void concat_kernel(const float* __restrict__ r2, const float* __restrict__ lat3,
                              float* __restrict__ x){
  int idx = blockIdx.x * blockDim.x + threadIdx.x;
  if (idx >= Gg * 640) return;
  int g = idx / 640, c = idx % 640;
  x[idx] = (c < 384) ? r2[g * 384 + c] : lat3[g * 256 + (c - 384)];
}

// ------------------------------------------------------------------
// bf16 MFMA GEMM: C[M,NC] = A[M,K] @ B[K,NC] (+bias)(+resid), fp32 out
// (+ optional bf16 shadow of C). B given PRE-TRANSPOSED: Bt[NC][K] bf16.
// Tile 128x128, 256 threads (4 waves), K-chunk 32, 16x16x32 MFMA.
//  MODE 0: A16 = plain bf16 row-major (lda)
//  MODE 2: cols<128 from A16=h16 (lda=128); cols>=128 from fp32 agg
//          (chunk-local, 512 wide), scaled by amp/att per row.
// NC must be a multiple of 128; K a multiple of 32.
// ------------------------------------------------------------------
template<int MODE>
__global__ __launch_bounds__(256)
void mgemm_kernel(const short* __restrict__ A16, int lda,
                  const short* __restrict__ Bt,
                  const float* __restrict__ bias,
                  const float* __restrict__ resid,
                  float* __restrict__ C, short* __restrict__ C16,
                  int M, int K, int NC,
                  const float* __restrict__ agg,
                  const float* __restrict__ amp,
                  const float* __restrict__ att)
{
  __shared__ short As[128][40];   // [row][k], +8 pad: bank-uniform b128 access
  __shared__ short Bs[128][40];   // [col][k]

  int tid = threadIdx.x;
  int row0 = blockIdx.y * 128;
  int col0 = blockIdx.x * 128;
  int wv = tid >> 6, ln = tid & 63;
  int lo = ln & 15, q = ln >> 4;

  fx4 acc[2][8];
#pragma unroll
  for (int rt = 0; rt < 2; rt++)
#pragma unroll
    for (int ct = 0; ct < 8; ct++) acc[rt][ct] = (fx4){0.f, 0.f, 0.f, 0.f};

  int srow = tid & 127;       // staging row (A) / col (B)
  int kh = tid >> 7;          // which 16-element half of the 32-k chunk

  for (int k0 = 0; k0 < K; k0 += 32){
    int gk = k0 + kh * 16;
    // ---- stage A ----
    {
      int grow = row0 + srow;
      short8 v0 = {0,0,0,0,0,0,0,0}, v1 = {0,0,0,0,0,0,0,0};
      if (grow < M){
        if (MODE == 0 || gk < 128){
          const short* p = A16 + (size_t)grow * lda + gk;
          v0 = *(const short8*)p;
          v1 = *(const short8*)(p + 8);
        } else {
          int base; float sc;
          if (gk < 640)      { base = gk - 128;  sc = 1.f; }
          else if (gk < 1152){ base = gk - 640;  sc = amp[grow]; }
          else               { base = gk - 1152; sc = att[grow]; }
          const float* p = agg + (size_t)grow * 512 + base;
#pragma unroll
          for (int j = 0; j < 8; j++) ((short*)&v0)[j] = bf16r(p[j] * sc);
#pragma unroll
          for (int j = 0; j < 8; j++) ((short*)&v1)[j] = bf16r(p[8 + j] * sc);
        }
      }
      *(short8*)&As[srow][kh * 16]     = v0;
      *(short8*)&As[srow][kh * 16 + 8] = v1;
    }
    // ---- stage B (Bt is [NC][K], contiguous in k) ----
    {
      const short* p = Bt + (size_t)(col0 + srow) * K + gk;
      *(short8*)&Bs[srow][kh * 16]     = *(const short8*)p;
      *(short8*)&Bs[srow][kh * 16 + 8] = *(const short8*)(p + 8);
    }
    __syncthreads();
    short8 af0 = *(const short8*)&As[wv * 32 + lo][q * 8];
    short8 af1 = *(const short8*)&As[wv * 32 + 16 + lo][q * 8];
#pragma unroll
    for (int ct = 0; ct < 8; ct++){
      short8 bf = *(const short8*)&Bs[ct * 16 + lo][q * 8];
      acc[0][ct] = __builtin_amdgcn_mfma_f32_16x16x32_bf16(af0, bf, acc[0][ct], 0, 0, 0);
      acc[1][ct] = __builtin_amdgcn_mfma_f32_16x16x32_bf16(af1, bf, acc[1][ct], 0, 0, 0);
    }
    __syncthreads();
  }

  // ---- epilogue: D[row=(lane>>4)*4+r][col=lane&15] per 16x16 tile ----
#pragma unroll
  for (int rt = 0; rt < 2; rt++){
#pragma unroll
    for (int r = 0; r < 4; r++){
      int row = row0 + wv * 32 + rt * 16 + q * 4 + r;
      if (row >= M) continue;
#pragma unroll
      for (int ct = 0; ct < 8; ct++){
        int col = col0 + ct * 16 + lo;
        float v = acc[rt][ct][r];
        if (bias)  v += bias[col];
        if (resid) v += resid[(size_t)row * NC + col];
        C[(size_t)row * NC + col] = v;
        if (C16) C16[(size_t)row * NC + col] = bf16r(v);
      }
    }
  }
}

// ------------------------------------------------------------------
// small fp32 GEMM (head + ezt): C = A @ B (+bias)(relu?)
// ------------------------------------------------------------------
template<bool RELU>
__global__ __launch_bounds__(256)
void gemm32_kernel(const float* __restrict__ A, const float* __restrict__ B,
                   const float* __restrict__ bias, float* __restrict__ C,
                   int M, int K, int NC)
{
  __shared__ __align__(16) float As[16][68];
  __shared__ __align__(16) float Bs[16][68];
  int tid = threadIdx.x;
  int row0 = blockIdx.y * 64, col0 = blockIdx.x * 64;
  float acc[4][4];
#pragma unroll
  for (int i = 0; i < 4; i++)
#pragma unroll
    for (int j = 0; j < 4; j++) acc[i][j] = 0.f;
  int tm = tid >> 4, tn = tid & 15;
  int kk_a = tid & 15, r_a = tid >> 4;
  int c_b = tid & 63, k_b = tid >> 6;
  for (int k0 = 0; k0 < K; k0 += 16){
#pragma unroll
    for (int i = 0; i < 4; i++){
      int rr = r_a + i * 16;
      int grow = row0 + rr;
      int gk = k0 + kk_a;
      float v = 0.f;
      if (grow < M && gk < K) v = A[(size_t)grow * K + gk];
      As[kk_a][rr] = v;
    }
#pragma unroll
    for (int i = 0; i < 4; i++){
      int kr = k_b + i * 4;
      int gk = k0 + kr;
      int gc = col0 + c_b;
      Bs[kr][c_b] = (gk < K && gc < NC) ? B[(size_t)gk * NC + gc] : 0.f;
    }
    __syncthreads();
#pragma unroll
    for (int kk = 0; kk < 16; kk++){
      float4 a = *(const float4*)&As[kk][tm * 4];
      float4 b = *(const float4*)&Bs[kk][tn * 4];
      acc[0][0] += a.x * b.x; acc[0][1] += a.x * b.y; acc[0][2] += a.x * b.z; acc[0][3] += a.x * b.w;
      acc[1][0] += a.y * b.x; acc[1][1] += a.y * b.y; acc[1][2] += a.y * b.z; acc[1][3] += a.y * b.w;
      acc[2][0] += a.z * b.x; acc[2][1] += a.z * b.y; acc[2][2] += a.z * b.z; acc[2][3] += a.z * b.w;
      acc[3][0] += a.w * b.x; acc[3][1] += a.w * b.y; acc[3][2] += a.w * b.z; acc[3][3] += a.w * b.w;
    }
    __syncthreads();
  }
#pragma unroll
  for (int i = 0; i < 4; i++){
    int r = row0 + tm * 4 + i;
    if (r >= M) continue;
#pragma unroll
    for (int j = 0; j < 4; j++){
      int c = col0 + tn * 4 + j;
      if (c >= NC) continue;
      float v = acc[i][j];
      if (bias) v += bias[c];
      if (RELU) v = fmaxf(v, 0.f);
      C[(size_t)r * NC + c] = v;
    }
  }
}

// ------------------------------------------------------------------
extern "C" void kernel_launch(void* const* d_in, const int* in_sizes, int n_in,
                              void* d_out, int out_size, void* d_ws, size_t ws_size,
                              hipStream_t stream)
{
  const int*   node_feat = (const int*)  d_in[0];
  const int*   edge_feat = (const int*)  d_in[1];
  const int*   src       = (const int*)  d_in[2];
  const int*   dst       = (const int*)  d_in[3];
  const float* aemb_f  = (const float*) d_in[5];
  const float* bemb_f  = (const float*) d_in[6];
  const float* w_pre_f = (const float*) d_in[7];
  const float* b_pre_f = (const float*) d_in[8];
  const float* w_post_f= (const float*) d_in[9];
  const float* b_post_f= (const float*) d_in[10];
  const float* w_out3  = (const float*) d_in[11];
  const float* b_out3  = (const float*) d_in[12];
  const float* aemb    = (const float*) d_in[13];
  const float* bemb    = (const float*) d_in[14];
  const float* w_pre   = (const float*) d_in[15];
  const float* b_pre   = (const float*) d_in[16];
  const float* w_post  = (const float*) d_in[17];
  const float* b_post  = (const float*) d_in[18];
  const float* w1      = (const float*) d_in[19];
  const float* b1      = (const float*) d_in[20];
  const float* w2      = (const float*) d_in[21];
  const float* b2      = (const float*) d_in[22];
  float* out = (float*)d_out;

  // ---- workspace carve (fixed ~147 MB), agg takes the rest ----
  char* w = (char*)d_ws;
  auto carve = [&](size_t bytes) -> void* {
    void* p = (void*)w;
    w += (bytes + 255) & ~(size_t)255;
    return p;
  };
  float* h_a    = (float*)carve((size_t)Nn * Hc * 4);
  float* h_b    = (float*)carve((size_t)Nn * Hc * 4);
  short* h16_a  = (short*)carve((size_t)Nn * Hc * 2);
  short* h16_b  = (short*)carve((size_t)Nn * Hc * 2);
  float* hsd    = (float*)carve((size_t)Nn * 256 * 4);
  short* btpost = (short*)carve((size_t)128 * 1664 * 2);
  short* btpre  = (short*)carve((size_t)256 * 128 * 2);
  float* bsum   = (float*)carve((size_t)125 * Hc * 4);
  float* ezt    = (float*)carve((size_t)125 * Hc * 4);
  float* amp    = (float*)carve((size_t)Nn * 4);
  float* att    = (float*)carve((size_t)Nn * 4);
  float* r3     = (float*)carve((size_t)Gg * 384 * 4);
  float* r2     = (float*)carve((size_t)Gg * 384 * 4);
  float* lat3   = (float*)carve((size_t)Gg * 256 * 4);
  float* xcat   = (float*)carve((size_t)Gg * 640 * 4);
  float* h1buf  = (float*)carve((size_t)Gg * Hc * 4);
  int* deg      = (int*)carve((size_t)Nn * 4);
  int* rowstart = (int*)carve((size_t)(Nn + 1) * 4);
  int* cursor   = (int*)carve((size_t)Nn * 4);
  int* src_srt  = (int*)carve((size_t)Ee * 4);
  int* code_srt = (int*)carve((size_t)Ee * 4);

  size_t fixed_bytes = (size_t)(w - (char*)d_ws);
  size_t avail = (ws_size > fixed_bytes) ? (ws_size - fixed_bytes) : 0;
  long max_rows = (long)(avail / (512 * 4));
  int chunk = (max_rows >= Nn) ? Nn : (int)(max_rows & ~127L);
  if (chunk < 128) chunk = 128;
  float* agg = (float*)w;   // chunk * 512 floats

  // ---- graph preprocessing ----
  hipMemsetAsync(deg, 0, (size_t)Nn * 4, stream);
  deg_kernel<<<(Ee + 255) / 256, 256, 0, stream>>>(dst, deg, Ee);
  scan_kernel<<<1, 1024, 0, stream>>>(deg, rowstart, Nn);
  copy_int_kernel<<<(Nn + 255) / 256, 256, 0, stream>>>(rowstart, cursor, Nn);
  scatter_kernel<<<(Ee + 255) / 256, 256, 0, stream>>>(src, dst, edge_feat, cursor,
                                                       src_srt, code_srt, Ee);
  ampatt_kernel<<<(Nn + 255) / 256, 256, 0, stream>>>(deg, amp, att, Nn);

  // ---- one PNA branch ----
  auto run_branch = [&](const float* aemb_p, const float* bemb_p,
                        const float* w_pre_p, const float* b_pre_p,
                        const float* w_post_p, const float* b_post_p,
                        float* r_out)
  {
    float* h_cur = h_a;   float* h_nxt = h_b;
    short* g_cur = h16_a; short* g_nxt = h16_b;
    embed_node_kernel<<<(Nn * Hc + 255) / 256, 256, 0, stream>>>(node_feat, aemb_p, h_cur, g_cur);
    bsum_kernel<<<(125 * Hc + 255) / 256, 256, 0, stream>>>(bemb_p, bsum);
    for (int l = 0; l < Lc; l++){
      const float* wl = w_pre_p + (size_t)l * 384 * 128;
      conv_wpre_kernel<<<(256 * 128 + 255) / 256, 256, 0, stream>>>(wl, btpre);
      conv_wpost_kernel<<<(1664 * 128 + 255) / 256, 256, 0, stream>>>(
          w_post_p + (size_t)l * 1664 * 128, btpost);
      // hsd = h16 @ [W_src|W_dst]  (bf16 MFMA, N=256)
      mgemm_kernel<0><<<dim3(2, (Nn + 127) / 128), 256, 0, stream>>>(
          g_cur, 128, btpre, nullptr, nullptr, hsd, nullptr, Nn, 128, 256,
          nullptr, nullptr, nullptr);
      // ezt = bsum @ W_e + b_pre (125 rows, fp32)
      gemm32_kernel<false><<<dim3(2, 2), 256, 0, stream>>>(
          bsum, wl + 256 * 128, b_pre_p + (size_t)l * 128, ezt, 125, 128, 128);
      // chunked: aggregation stats then bf16 MFMA post-GEMM
      for (int n0 = 0; n0 < Nn; n0 += chunk){
        int rows = (Nn - n0 < chunk) ? (Nn - n0) : chunk;
        agg_kernel<<<rows, 128, 0, stream>>>(hsd, ezt, src_srt, code_srt, rowstart, agg, n0);
        mgemm_kernel<2><<<dim3(1, (rows + 127) / 128), 256, 0, stream>>>(
            g_cur + (size_t)n0 * Hc, 128, btpost, b_post_p + (size_t)l * 128,
            h_cur + (size_t)n0 * Hc,
            h_nxt + (size_t)n0 * Hc, g_nxt + (size_t)n0 * Hc,
            rows, 1664, 128, agg, amp + n0, att + n0);
      }
      { float* t = h_cur; h_cur = h_nxt; h_nxt = t; }
      { short* t = g_cur; g_cur = g_nxt; g_nxt = t; }
    }
    readout_kernel<<<Gg, 128, 0, stream>>>(h_cur, r_out);
  };

  // frozen 3D branch -> latent3d
  run_branch(aemb_f, bemb_f, w_pre_f, b_pre_f, w_post_f, b_post_f, r3);
  gemm32_kernel<false><<<dim3(4, (Gg + 63) / 64), 256, 0, stream>>>(
      r3, w_out3, b_out3, lat3, Gg, 384, 256);

  // trainable 2D branch
  run_branch(aemb, bemb, w_pre, b_pre, w_post, b_post, r2);

  // head
  concat_kernel<<<(Gg * 640 + 255) / 256, 256, 0, stream>>>(r2, lat3, xcat);
  gemm32_kernel<true><<<dim3(2, (Gg + 63) / 64), 256, 0, stream>>>(
      xcat, w1, b1, h1buf, Gg, 640, 128);
  gemm32_kernel<false><<<dim3(2, (Gg + 63) / 64), 256, 0, stream>>>(
      h1buf, w2, b2, out, Gg, 128, 128);
}

// Round 4
// 2394.271 us; speedup vs baseline: 2.7914x; 1.1903x over previous
//
#include <hip/hip_runtime.h>
#include <hip/hip_bf16.h>
#include <math.h>

// Problem constants (fixed by the reference)
#define Nn 50000
#define Ee 400000
#define Gg 2000
#define NPGc 25
#define Hc 128
#define Lc 5

typedef __attribute__((ext_vector_type(8))) short short8;   // 8 bf16 = 4 VGPRs
typedef __attribute__((ext_vector_type(4))) float fx4;      // MFMA accumulator

// round-to-nearest-even fp32 -> bf16 (raw short)
__device__ inline short bf16r(float x){
  unsigned u = __float_as_uint(x);
  unsigned r = (u + 0x7fffu + ((u >> 16) & 1u)) >> 16;
  return (short)r;
}
__device__ inline float bf16f(short s){
  return __uint_as_float(((unsigned)(unsigned short)s) << 16);
}

// ------------------------------------------------------------------
// Graph preprocessing (once per call, shared by branches)
// ------------------------------------------------------------------
__global__ void deg_kernel(const int* __restrict__ dst, int* __restrict__ deg, int E){
  int i = blockIdx.x * blockDim.x + threadIdx.x;
  if (i < E) atomicAdd(&deg[dst[i]], 1);
}

__global__ void scan_kernel(const int* __restrict__ deg, int* __restrict__ rowstart, int n){
  __shared__ int tmp[1024];
  int tid = threadIdx.x;
  if (tid == 0) rowstart[0] = 0;
  int base = 0;
  for (int start = 0; start < n; start += 1024){
    int i = start + tid;
    int v = (i < n) ? deg[i] : 0;
    tmp[tid] = v;
    __syncthreads();
    for (int off = 1; off < 1024; off <<= 1){
      int add = (tid >= off) ? tmp[tid - off] : 0;
      __syncthreads();
      tmp[tid] += add;
      __syncthreads();
    }
    if (i < n) rowstart[i + 1] = base + tmp[tid];
    base += tmp[1023];
    __syncthreads();
  }
}

__global__ void copy_int_kernel(const int* __restrict__ a, int* __restrict__ b, int n){
  int i = blockIdx.x * blockDim.x + threadIdx.x;
  if (i < n) b[i] = a[i];
}

__global__ void scatter_kernel(const int* __restrict__ src, const int* __restrict__ dst,
                               const int* __restrict__ ef, int* cursor,
                               int* __restrict__ src_srt, int* __restrict__ code_srt, int E){
  int i = blockIdx.x * blockDim.x + threadIdx.x;
  if (i >= E) return;
  int p = atomicAdd(&cursor[dst[i]], 1);
  src_srt[p] = src[i];
  code_srt[p] = ef[i * 3 + 0] * 25 + ef[i * 3 + 1] * 5 + ef[i * 3 + 2];
}

__global__ void ampatt_kernel(const int* __restrict__ deg, float* __restrict__ amp,
                              float* __restrict__ att, int n){
  int i = blockIdx.x * blockDim.x + threadIdx.x;
  if (i >= n) return;
  float d = (float)deg[i];
  float ld = logf(d + 1.0f);
  amp[i] = ld;
  att[i] = (deg[i] > 0) ? (1.0f / ld) : 0.0f;
}

// ------------------------------------------------------------------
// Node embedding: h fp32 + bf16 shadow
// ------------------------------------------------------------------
__global__ void embed_node_kernel(const int* __restrict__ nf, const float* __restrict__ aemb,
                                  float* __restrict__ h, short* __restrict__ h16){
  int idx = blockIdx.x * blockDim.x + threadIdx.x;
  if (idx >= Nn * Hc) return;
  int n = idx >> 7, c = idx & 127;
  float s = 0.f;
#pragma unroll
  for (int f = 0; f < 9; f++){
    int row = nf[n * 9 + f] + 16 * f;
    s += aemb[row * Hc + c];
  }
  h[idx] = s;
  h16[idx] = bf16r(s);
}

// bsum[code][c]: 125 distinct edge embeddings
__global__ void bsum_kernel(const float* __restrict__ bemb, float* __restrict__ bsum){
  int idx = blockIdx.x * blockDim.x + threadIdx.x;
  if (idx >= 125 * Hc) return;
  int code = idx >> 7, c = idx & 127;
  int e0 = code / 25, e1 = (code / 5) % 5, e2 = code % 5;
  bsum[idx] = bemb[e0 * Hc + c] + bemb[(5 + e1) * Hc + c] + bemb[(10 + e2) * Hc + c];
}

// ------------------------------------------------------------------
// per-layer weight converts (tiny)
__global__ void conv_wpost_kernel(const float* __restrict__ w, short* __restrict__ Bt){
  int idx = blockIdx.x * blockDim.x + threadIdx.x;
  if (idx >= 1664 * 128) return;
  int k = idx >> 7, c = idx & 127;
  Bt[(size_t)c * 1664 + k] = bf16r(w[idx]);
}
__global__ void conv_wpre_kernel(const float* __restrict__ wl, short* __restrict__ Btp){
  int idx = blockIdx.x * blockDim.x + threadIdx.x;
  if (idx >= 256 * 128) return;
  int col = idx >> 7, k = idx & 127;
  float v = (col < 128) ? wl[k * 128 + col] : wl[(128 + k) * 128 + (col - 128)];
  Btp[col * 128 + k] = bf16r(v);
}

// ------------------------------------------------------------------
// PNA aggregation: z_k = hs[src_k] + hd[n] + ezt[code_k]
// hsd is [N][256] fp32: cols 0..127 = hs, 128..255 = hd
// agg16 out: bf16 [chunkrow][512] = mean | max | min | std
// ------------------------------------------------------------------
__global__ void agg_kernel(const float* __restrict__ hsd, const float* __restrict__ ezt,
                           const int* __restrict__ src_srt, const int* __restrict__ code_srt,
                           const int* __restrict__ rowstart,
                           short* __restrict__ agg16, int n0){
  int n = n0 + blockIdx.x;
  int c = threadIdx.x;
  int s0 = rowstart[n], s1 = rowstart[n + 1];
  short* out = agg16 + (size_t)blockIdx.x * 512;
  if (s1 == s0){
    out[c] = 0; out[128 + c] = 0; out[256 + c] = 0; out[384 + c] = 0;
    return;
  }
  float hdc = hsd[(size_t)n * 256 + 128 + c];
  float sum = 0.f, sum2 = 0.f, mx = -3.402823466e38f, mn = 3.402823466e38f;
  for (int k = s0; k < s1; k++){
    int sidx = src_srt[k];
    float z = hsd[(size_t)sidx * 256 + c] + hdc + ezt[(size_t)code_srt[k] * Hc + c];
    sum += z; sum2 += z * z;
    mx = fmaxf(mx, z); mn = fminf(mn, z);
  }
  float d  = (float)(s1 - s0);
  float m  = sum / d;
  float ms = sum2 / d;
  float var = ms - m * m;
  var = var > 0.f ? var : 0.f;
  out[c]       = bf16r(m);
  out[128 + c] = bf16r(mx);
  out[256 + c] = bf16r(mn);
  out[384 + c] = bf16r(sqrtf(var + 1e-5f));
}

// ------------------------------------------------------------------
// Graph readout: [min | max | mean]
// ------------------------------------------------------------------
__global__ void readout_kernel(const float* __restrict__ h, float* __restrict__ r){
  int g = blockIdx.x, c = threadIdx.x;
  float mn = 3.402823466e38f, mx = -3.402823466e38f, s = 0.f;
  const float* hp = h + (size_t)g * NPGc * Hc + c;
#pragma unroll
  for (int i = 0; i < NPGc; i++){
    float v = hp[i * Hc];
    mn = fminf(mn, v); mx = fmaxf(mx, v); s += v;
  }
  r[(size_t)g * 384 + c]       = mn;
  r[(size_t)g * 384 + 128 + c] = mx;
  r[(size_t)g * 384 + 256 + c] = s * (1.0f / NPGc);
}

__global__ void concat_kernel(const float* __restrict__ r2, const float* __restrict__ lat3,
                              float* __restrict__ x){
  int idx = blockIdx.x * blockDim.x + threadIdx.x;
  if (idx >= Gg * 640) return;
  int g = idx / 640, c = idx % 640;
  x[idx] = (c < 384) ? r2[g * 384 + c] : lat3[g * 256 + (c - 384)];
}

// ------------------------------------------------------------------
// bf16 MFMA GEMM, 64x128 tile (grid-parallelism-first):
// C[M,NC] = A[M,K] @ B (+bias)(+resid), fp32 out (+bf16 shadow).
// Bt PRE-TRANSPOSED [NC][K] bf16. 256 threads = 4 waves; each wave owns
// 16 rows x 128 cols (8 acc tiles). K-chunk 32, 16x16x32 MFMA.
//  MODE 0: A16 row-major bf16 (lda)
//  MODE 2: k<128 from A16=h16; k>=128 from bf16 agg16 (chunk-local,
//          512 wide), scaled by amp/att per row for the 2nd/3rd copies.
// ------------------------------------------------------------------
template<int MODE>
__global__ __launch_bounds__(256)
void mgemm_kernel(const short* __restrict__ A16, int lda,
                  const short* __restrict__ Bt,
                  const float* __restrict__ bias,
                  const float* __restrict__ resid,
                  float* __restrict__ C, short* __restrict__ C16,
                  int M, int K, int NC,
                  const short* __restrict__ agg16,
                  const float* __restrict__ amp,
                  const float* __restrict__ att)
{
  __shared__ short As[64][40];    // [row][k], +8 pad
  __shared__ short Bs[128][40];   // [col][k]

  int tid = threadIdx.x;
  int row0 = blockIdx.y * 64;
  int col0 = blockIdx.x * 128;
  int wv = tid >> 6, ln = tid & 63;
  int lo = ln & 15, q = ln >> 4;

  fx4 acc[8];
#pragma unroll
  for (int ct = 0; ct < 8; ct++) acc[ct] = (fx4){0.f, 0.f, 0.f, 0.f};

  int a_row = tid >> 2;          // 0..63
  int a_ko  = (tid & 3) * 8;     // 0,8,16,24
  int b_col = tid & 127;         // 0..127
  int b_kh  = (tid >> 7) * 16;   // 0 or 16

  for (int k0 = 0; k0 < K; k0 += 32){
    // ---- stage A: one short8 per thread ----
    {
      int grow = row0 + a_row;
      int gk = k0 + a_ko;
      short8 v = {0,0,0,0,0,0,0,0};
      if (grow < M){
        if (MODE == 0 || gk < 128){
          v = *(const short8*)(A16 + (size_t)grow * lda + gk);
        } else {
          if (gk < 640){
            v = *(const short8*)(agg16 + (size_t)grow * 512 + (gk - 128));
          } else {
            int base; float sc;
            if (gk < 1152){ base = gk - 640;  sc = amp[grow]; }
            else          { base = gk - 1152; sc = att[grow]; }
            short8 t = *(const short8*)(agg16 + (size_t)grow * 512 + base);
#pragma unroll
            for (int j = 0; j < 8; j++) ((short*)&v)[j] = bf16r(bf16f(((short*)&t)[j]) * sc);
          }
        }
      }
      *(short8*)&As[a_row][a_ko] = v;
    }
    // ---- stage B: two short8 per thread (Bt contiguous in k) ----
    {
      const short* p = Bt + (size_t)(col0 + b_col) * K + k0 + b_kh;
      *(short8*)&Bs[b_col][b_kh]     = *(const short8*)p;
      *(short8*)&Bs[b_col][b_kh + 8] = *(const short8*)(p + 8);
    }
    __syncthreads();
    short8 af = *(const short8*)&As[wv * 16 + lo][q * 8];
#pragma unroll
    for (int ct = 0; ct < 8; ct++){
      short8 bf = *(const short8*)&Bs[ct * 16 + lo][q * 8];
      acc[ct] = __builtin_amdgcn_mfma_f32_16x16x32_bf16(af, bf, acc[ct], 0, 0, 0);
    }
    __syncthreads();
  }

  // ---- epilogue: D[row=q*4+r][col=lo] per 16x16 tile ----
#pragma unroll
  for (int r = 0; r < 4; r++){
    int row = row0 + wv * 16 + q * 4 + r;
    if (row >= M) continue;
#pragma unroll
    for (int ct = 0; ct < 8; ct++){
      int col = col0 + ct * 16 + lo;
      float v = acc[ct][r];
      if (bias)  v += bias[col];
      if (resid) v += resid[(size_t)row * NC + col];
      C[(size_t)row * NC + col] = v;
      if (C16) C16[(size_t)row * NC + col] = bf16r(v);
    }
  }
}

// ------------------------------------------------------------------
// small fp32 GEMM (head + ezt): C = A @ B (+bias)(relu?)
// ------------------------------------------------------------------
template<bool RELU>
__global__ __launch_bounds__(256)
void gemm32_kernel(const float* __restrict__ A, const float* __restrict__ B,
                   const float* __restrict__ bias, float* __restrict__ C,
                   int M, int K, int NC)
{
  __shared__ __align__(16) float As[16][68];
  __shared__ __align__(16) float Bs[16][68];
  int tid = threadIdx.x;
  int row0 = blockIdx.y * 64, col0 = blockIdx.x * 64;
  float acc[4][4];
#pragma unroll
  for (int i = 0; i < 4; i++)
#pragma unroll
    for (int j = 0; j < 4; j++) acc[i][j] = 0.f;
  int tm = tid >> 4, tn = tid & 15;
  int kk_a = tid & 15, r_a = tid >> 4;
  int c_b = tid & 63, k_b = tid >> 6;
  for (int k0 = 0; k0 < K; k0 += 16){
#pragma unroll
    for (int i = 0; i < 4; i++){
      int rr = r_a + i * 16;
      int grow = row0 + rr;
      int gk = k0 + kk_a;
      float v = 0.f;
      if (grow < M && gk < K) v = A[(size_t)grow * K + gk];
      As[kk_a][rr] = v;
    }
#pragma unroll
    for (int i = 0; i < 4; i++){
      int kr = k_b + i * 4;
      int gk = k0 + kr;
      int gc = col0 + c_b;
      Bs[kr][c_b] = (gk < K && gc < NC) ? B[(size_t)gk * NC + gc] : 0.f;
    }
    __syncthreads();
#pragma unroll
    for (int kk = 0; kk < 16; kk++){
      float4 a = *(const float4*)&As[kk][tm * 4];
      float4 b = *(const float4*)&Bs[kk][tn * 4];
      acc[0][0] += a.x * b.x; acc[0][1] += a.x * b.y; acc[0][2] += a.x * b.z; acc[0][3] += a.x * b.w;
      acc[1][0] += a.y * b.x; acc[1][1] += a.y * b.y; acc[1][2] += a.y * b.z; acc[1][3] += a.y * b.w;
      acc[2][0] += a.z * b.x; acc[2][1] += a.z * b.y; acc[2][2] += a.z * b.z; acc[2][3] += a.z * b.w;
      acc[3][0] += a.w * b.x; acc[3][1] += a.w * b.y; acc[3][2] += a.w * b.z; acc[3][3] += a.w * b.w;
    }
    __syncthreads();
  }
#pragma unroll
  for (int i = 0; i < 4; i++){
    int r = row0 + tm * 4 + i;
    if (r >= M) continue;
#pragma unroll
    for (int j = 0; j < 4; j++){
      int c = col0 + tn * 4 + j;
      if (c >= NC) continue;
      float v = acc[i][j];
      if (bias) v += bias[c];
      if (RELU) v = fmaxf(v, 0.f);
      C[(size_t)r * NC + c] = v;
    }
  }
}

// ------------------------------------------------------------------
extern "C" void kernel_launch(void* const* d_in, const int* in_sizes, int n_in,
                              void* d_out, int out_size, void* d_ws, size_t ws_size,
                              hipStream_t stream)
{
  const int*   node_feat = (const int*)  d_in[0];
  const int*   edge_feat = (const int*)  d_in[1];
  const int*   src       = (const int*)  d_in[2];
  const int*   dst       = (const int*)  d_in[3];
  const float* aemb_f  = (const float*) d_in[5];
  const float* bemb_f  = (const float*) d_in[6];
  const float* w_pre_f = (const float*) d_in[7];
  const float* b_pre_f = (const float*) d_in[8];
  const float* w_post_f= (const float*) d_in[9];
  const float* b_post_f= (const float*) d_in[10];
  const float* w_out3  = (const float*) d_in[11];
  const float* b_out3  = (const float*) d_in[12];
  const float* aemb    = (const float*) d_in[13];
  const float* bemb    = (const float*) d_in[14];
  const float* w_pre   = (const float*) d_in[15];
  const float* b_pre   = (const float*) d_in[16];
  const float* w_post  = (const float*) d_in[17];
  const float* b_post  = (const float*) d_in[18];
  const float* w1      = (const float*) d_in[19];
  const float* b1      = (const float*) d_in[20];
  const float* w2      = (const float*) d_in[21];
  const float* b2      = (const float*) d_in[22];
  float* out = (float*)d_out;

  // ---- workspace carve ----
  char* w = (char*)d_ws;
  auto carve = [&](size_t bytes) -> void* {
    void* p = (void*)w;
    w += (bytes + 255) & ~(size_t)255;
    return p;
  };
  float* h_a    = (float*)carve((size_t)Nn * Hc * 4);
  float* h_b    = (float*)carve((size_t)Nn * Hc * 4);
  short* h16_a  = (short*)carve((size_t)Nn * Hc * 2);
  short* h16_b  = (short*)carve((size_t)Nn * Hc * 2);
  float* hsd    = (float*)carve((size_t)Nn * 256 * 4);
  short* btpost = (short*)carve((size_t)128 * 1664 * 2);
  short* btpre  = (short*)carve((size_t)256 * 128 * 2);
  float* bsum   = (float*)carve((size_t)125 * Hc * 4);
  float* ezt    = (float*)carve((size_t)125 * Hc * 4);
  float* amp    = (float*)carve((size_t)Nn * 4);
  float* att    = (float*)carve((size_t)Nn * 4);
  float* r3     = (float*)carve((size_t)Gg * 384 * 4);
  float* r2     = (float*)carve((size_t)Gg * 384 * 4);
  float* lat3   = (float*)carve((size_t)Gg * 256 * 4);
  float* xcat   = (float*)carve((size_t)Gg * 640 * 4);
  float* h1buf  = (float*)carve((size_t)Gg * Hc * 4);
  int* deg      = (int*)carve((size_t)Nn * 4);
  int* rowstart = (int*)carve((size_t)(Nn + 1) * 4);
  int* cursor   = (int*)carve((size_t)Nn * 4);
  int* src_srt  = (int*)carve((size_t)Ee * 4);
  int* code_srt = (int*)carve((size_t)Ee * 4);

  size_t fixed_bytes = (size_t)(w - (char*)d_ws);
  size_t avail = (ws_size > fixed_bytes) ? (ws_size - fixed_bytes) : 0;
  long max_rows = (long)(avail / (512 * 2));
  int chunk = (max_rows >= Nn) ? Nn : (int)(max_rows & ~127L);
  if (chunk < 128) chunk = 128;
  short* agg16 = (short*)w;   // chunk * 512 bf16

  // ---- graph preprocessing ----
  hipMemsetAsync(deg, 0, (size_t)Nn * 4, stream);
  deg_kernel<<<(Ee + 255) / 256, 256, 0, stream>>>(dst, deg, Ee);
  scan_kernel<<<1, 1024, 0, stream>>>(deg, rowstart, Nn);
  copy_int_kernel<<<(Nn + 255) / 256, 256, 0, stream>>>(rowstart, cursor, Nn);
  scatter_kernel<<<(Ee + 255) / 256, 256, 0, stream>>>(src, dst, edge_feat, cursor,
                                                       src_srt, code_srt, Ee);
  ampatt_kernel<<<(Nn + 255) / 256, 256, 0, stream>>>(deg, amp, att, Nn);

  // ---- one PNA branch ----
  auto run_branch = [&](const float* aemb_p, const float* bemb_p,
                        const float* w_pre_p, const float* b_pre_p,
                        const float* w_post_p, const float* b_post_p,
                        float* r_out)
  {
    float* h_cur = h_a;   float* h_nxt = h_b;
    short* g_cur = h16_a; short* g_nxt = h16_b;
    embed_node_kernel<<<(Nn * Hc + 255) / 256, 256, 0, stream>>>(node_feat, aemb_p, h_cur, g_cur);
    bsum_kernel<<<(125 * Hc + 255) / 256, 256, 0, stream>>>(bemb_p, bsum);
    for (int l = 0; l < Lc; l++){
      const float* wl = w_pre_p + (size_t)l * 384 * 128;
      conv_wpre_kernel<<<(256 * 128 + 255) / 256, 256, 0, stream>>>(wl, btpre);
      conv_wpost_kernel<<<(1664 * 128 + 255) / 256, 256, 0, stream>>>(
          w_post_p + (size_t)l * 1664 * 128, btpost);
      // hsd = h16 @ [W_src|W_dst]  (bf16 MFMA, NC=256)
      mgemm_kernel<0><<<dim3(2, (Nn + 63) / 64), 256, 0, stream>>>(
          g_cur, 128, btpre, nullptr, nullptr, hsd, nullptr, Nn, 128, 256,
          nullptr, nullptr, nullptr);
      // ezt = bsum @ W_e + b_pre (125 rows, fp32)
      gemm32_kernel<false><<<dim3(2, 2), 256, 0, stream>>>(
          bsum, wl + 256 * 128, b_pre_p + (size_t)l * 128, ezt, 125, 128, 128);
      // chunked: aggregation stats (bf16 out) then bf16 MFMA post-GEMM
      for (int n0 = 0; n0 < Nn; n0 += chunk){
        int rows = (Nn - n0 < chunk) ? (Nn - n0) : chunk;
        agg_kernel<<<rows, 128, 0, stream>>>(hsd, ezt, src_srt, code_srt, rowstart, agg16, n0);
        mgemm_kernel<2><<<dim3(1, (rows + 63) / 64), 256, 0, stream>>>(
            g_cur + (size_t)n0 * Hc, 128, btpost, b_post_p + (size_t)l * 128,
            h_cur + (size_t)n0 * Hc,
            h_nxt + (size_t)n0 * Hc, g_nxt + (size_t)n0 * Hc,
            rows, 1664, 128, agg16, amp + n0, att + n0);
      }
      { float* t = h_cur; h_cur = h_nxt; h_nxt = t; }
      { short* t = g_cur; g_cur = g_nxt; g_nxt = t; }
    }
    readout_kernel<<<Gg, 128, 0, stream>>>(h_cur, r_out);
  };

  // frozen 3D branch -> latent3d
  run_branch(aemb_f, bemb_f, w_pre_f, b_pre_f, w_post_f, b_post_f, r3);
  gemm32_kernel<false><<<dim3(4, (Gg + 63) / 64), 256, 0, stream>>>(
      r3, w_out3, b_out3, lat3, Gg, 384, 256);

  // trainable 2D branch
  run_branch(aemb, bemb, w_pre, b_pre, w_post, b_post, r2);

  // head
  concat_kernel<<<(Gg * 640 + 255) / 256, 256, 0, stream>>>(r2, lat3, xcat);
  gemm32_kernel<true><<<dim3(2, (Gg + 63) / 64), 256, 0, stream>>>(
      xcat, w1, b1, h1buf, Gg, 640, 128);
  gemm32_kernel<false><<<dim3(2, (Gg + 63) / 64), 256, 0, stream>>>(
      h1buf, w2, b2, out, Gg, 128, 128);
}

// Round 5
// 2046.782 us; speedup vs baseline: 3.2653x; 1.1698x over previous
//
#include <hip/hip_runtime.h>
#include <hip/hip_bf16.h>
#include <math.h>

// Problem constants (fixed by the reference)
#define Nn 50000
#define Ee 400000
#define Gg 2000
#define NPGc 25
#define Hc 128
#define Lc 5

typedef __attribute__((ext_vector_type(8))) short short8;   // 8 bf16 = 4 VGPRs
typedef __attribute__((ext_vector_type(4))) float fx4;      // MFMA accumulator

__device__ inline short bf16r(float x){
  unsigned u = __float_as_uint(x);
  unsigned r = (u + 0x7fffu + ((u >> 16) & 1u)) >> 16;
  return (short)r;
}
__device__ inline float bf16f(short s){
  return __uint_as_float(((unsigned)(unsigned short)s) << 16);
}

// ------------------------------------------------------------------
// Graph preprocessing
// ------------------------------------------------------------------
__global__ void deg_kernel(const int* __restrict__ dst, int* __restrict__ deg, int E){
  int i = blockIdx.x * blockDim.x + threadIdx.x;
  if (i < E) atomicAdd(&deg[dst[i]], 1);
}

// 3-phase parallel exclusive scan (rowstart[i+1] = incl_scan(deg)[i])
__global__ void scan1_kernel(const int* __restrict__ deg, int* __restrict__ part,
                             int* __restrict__ bsums, int n){
  __shared__ int tmp[1024];
  int b = blockIdx.x, t = threadIdx.x;
  int i = b * 1024 + t;
  int v = (i < n) ? deg[i] : 0;
  tmp[t] = v;
  __syncthreads();
  for (int off = 1; off < 1024; off <<= 1){
    int add = (t >= off) ? tmp[t - off] : 0;
    __syncthreads();
    tmp[t] += add;
    __syncthreads();
  }
  part[i] = tmp[t];              // inclusive within block
  if (t == 1023) bsums[b] = tmp[1023];
}
__global__ void scan2_kernel(int* __restrict__ bsums, int nb){
  if (threadIdx.x == 0){
    int s = 0;
    for (int i = 0; i < nb; i++){ s += bsums[i]; bsums[i] = s; }
  }
}
__global__ void scan3_kernel(const int* __restrict__ part, const int* __restrict__ bsums,
                             int* __restrict__ rowstart, int n){
  int i = blockIdx.x * blockDim.x + threadIdx.x;
  if (i == 0) rowstart[0] = 0;
  if (i < n){
    int b = i >> 10;
    int base = b ? bsums[b - 1] : 0;
    rowstart[i + 1] = part[i] + base;
  }
}

__global__ void copy_int_kernel(const int* __restrict__ a, int* __restrict__ b, int n){
  int i = blockIdx.x * blockDim.x + threadIdx.x;
  if (i < n) b[i] = a[i];
}

__global__ void scatter_kernel(const int* __restrict__ src, const int* __restrict__ dst,
                               const int* __restrict__ ef, int* cursor,
                               int* __restrict__ src_srt, int* __restrict__ code_srt, int E){
  int i = blockIdx.x * blockDim.x + threadIdx.x;
  if (i >= E) return;
  int p = atomicAdd(&cursor[dst[i]], 1);
  src_srt[p] = src[i];
  code_srt[p] = ef[i * 3 + 0] * 25 + ef[i * 3 + 1] * 5 + ef[i * 3 + 2];
}

__global__ void ampatt_kernel(const int* __restrict__ deg, float* __restrict__ amp,
                              float* __restrict__ att, int n){
  int i = blockIdx.x * blockDim.x + threadIdx.x;
  if (i >= n) return;
  float d = (float)deg[i];
  float ld = logf(d + 1.0f);
  amp[i] = ld;
  att[i] = (deg[i] > 0) ? (1.0f / ld) : 0.0f;
}

// ------------------------------------------------------------------
// Node embedding: h fp32 + bf16 shadow
// ------------------------------------------------------------------
__global__ void embed_node_kernel(const int* __restrict__ nf, const float* __restrict__ aemb,
                                  float* __restrict__ h, short* __restrict__ h16){
  int idx = blockIdx.x * blockDim.x + threadIdx.x;
  if (idx >= Nn * Hc) return;
  int n = idx >> 7, c = idx & 127;
  float s = 0.f;
#pragma unroll
  for (int f = 0; f < 9; f++){
    int row = nf[n * 9 + f] + 16 * f;
    s += aemb[row * Hc + c];
  }
  h[idx] = s;
  h16[idx] = bf16r(s);
}

// bsum2[b][code][c]: 125 distinct edge embeddings, both branches
__global__ void bsum2_kernel(const float* __restrict__ bemb_f, const float* __restrict__ bemb_t,
                             float* __restrict__ bsum2){
  int idx = blockIdx.x * blockDim.x + threadIdx.x;
  if (idx >= 2 * 125 * Hc) return;
  int b = idx / (125 * Hc);
  int rem = idx % (125 * Hc);
  int code = rem >> 7, c = rem & 127;
  int e0 = code / 25, e1 = (code / 5) % 5, e2 = code % 5;
  const float* bemb = b ? bemb_t : bemb_f;
  bsum2[idx] = bemb[e0 * Hc + c] + bemb[(5 + e1) * Hc + c] + bemb[(10 + e2) * Hc + c];
}

// ------------------------------------------------------------------
// up-front weight converts, both branches x 5 layers
// ------------------------------------------------------------------
__global__ void conv_pre_all_kernel(const float* __restrict__ wpre_f,
                                    const float* __restrict__ wpre_t,
                                    short* __restrict__ btpre_all){
  int idx = blockIdx.x * blockDim.x + threadIdx.x;
  if (idx >= 2 * Lc * 256 * 128) return;
  int bl = idx / (256 * 128);          // 0..9
  int rem = idx % (256 * 128);
  int col = rem >> 7, k = rem & 127;
  int b = bl / Lc, l = bl % Lc;
  const float* wl = (b ? wpre_t : wpre_f) + (size_t)l * 384 * 128;
  float v = (col < 128) ? wl[k * 128 + col] : wl[(128 + k) * 128 + (col - 128)];
  btpre_all[(size_t)bl * 256 * 128 + col * 128 + k] = bf16r(v);
}
__global__ void conv_post_all_kernel(const float* __restrict__ wpost_f,
                                     const float* __restrict__ wpost_t,
                                     short* __restrict__ btpost_all){
  int idx = blockIdx.x * blockDim.x + threadIdx.x;
  if (idx >= 2 * Lc * 1664 * 128) return;
  int bl = idx / (1664 * 128);
  int rem = idx % (1664 * 128);
  int k = rem >> 7, c = rem & 127;
  int b = bl / Lc, l = bl % Lc;
  const float* wl = (b ? wpost_t : wpost_f) + (size_t)l * 1664 * 128;
  btpost_all[(size_t)bl * 128 * 1664 + (size_t)c * 1664 + k] = bf16r(wl[(size_t)k * 128 + c]);
}

// ezt_all[bl][code][c] = bsum2[b][code][:] @ W_e[b,l] + b_pre[b,l]
__global__ void ezt_all_kernel(const float* __restrict__ wpre_f, const float* __restrict__ wpre_t,
                               const float* __restrict__ bpre_f, const float* __restrict__ bpre_t,
                               const float* __restrict__ bsum2, float* __restrict__ ezt_all){
  int code = blockIdx.x;      // 0..124
  int bl   = blockIdx.y;      // 0..9
  int t = threadIdx.x;        // 0..127
  int b = bl / Lc, l = bl % Lc;
  const float* wl = (b ? wpre_t : wpre_f) + (size_t)l * 384 * 128 + 256 * 128;
  const float* bp = (b ? bpre_t : bpre_f) + (size_t)l * 128;
  __shared__ float bs[128];
  bs[t] = bsum2[((size_t)b * 125 + code) * 128 + t];
  __syncthreads();
  float acc = bp[t];
#pragma unroll 8
  for (int k = 0; k < 128; k++) acc += bs[k] * wl[k * 128 + t];
  ezt_all[((size_t)bl * 125 + code) * 128 + t] = acc;
}

// ------------------------------------------------------------------
// PNA aggregation: z_k = hs16[src_k] + hd16[n] + ezt[code_k]
// hsd16 bf16 [N][256]: cols 0..127 = hs, 128..255 = hd
// agg16 out bf16 [chunkrow][512] = mean | max | min | std
// ------------------------------------------------------------------
__global__ void agg_kernel(const short* __restrict__ hsd16, const float* __restrict__ ezt,
                           const int* __restrict__ src_srt, const int* __restrict__ code_srt,
                           const int* __restrict__ rowstart,
                           short* __restrict__ agg16, int n0){
  int n = n0 + blockIdx.x;
  int c = threadIdx.x;
  int s0 = rowstart[n], s1 = rowstart[n + 1];
  short* out = agg16 + (size_t)blockIdx.x * 512;
  if (s1 == s0){
    out[c] = 0; out[128 + c] = 0; out[256 + c] = 0; out[384 + c] = 0;
    return;
  }
  float hdc = bf16f(hsd16[(size_t)n * 256 + 128 + c]);
  float sum = 0.f, sum2 = 0.f, mx = -3.402823466e38f, mn = 3.402823466e38f;
  for (int k = s0; k < s1; k++){
    int sidx = src_srt[k];
    float z = bf16f(hsd16[(size_t)sidx * 256 + c]) + hdc + ezt[(size_t)code_srt[k] * Hc + c];
    sum += z; sum2 += z * z;
    mx = fmaxf(mx, z); mn = fminf(mn, z);
  }
  float d  = (float)(s1 - s0);
  float m  = sum / d;
  float ms = sum2 / d;
  float var = ms - m * m;
  var = var > 0.f ? var : 0.f;
  out[c]       = bf16r(m);
  out[128 + c] = bf16r(mx);
  out[256 + c] = bf16r(mn);
  out[384 + c] = bf16r(sqrtf(var + 1e-5f));
}

// ------------------------------------------------------------------
// Graph readout: [min | max | mean]
// ------------------------------------------------------------------
__global__ void readout_kernel(const float* __restrict__ h, float* __restrict__ r){
  int g = blockIdx.x, c = threadIdx.x;
  float mn = 3.402823466e38f, mx = -3.402823466e38f, s = 0.f;
  const float* hp = h + (size_t)g * NPGc * Hc + c;
#pragma unroll
  for (int i = 0; i < NPGc; i++){
    float v = hp[i * Hc];
    mn = fminf(mn, v); mx = fmaxf(mx, v); s += v;
  }
  r[(size_t)g * 384 + c]       = mn;
  r[(size_t)g * 384 + 128 + c] = mx;
  r[(size_t)g * 384 + 256 + c] = s * (1.0f / NPGc);
}

// ------------------------------------------------------------------
// Fused head: per 8 graphs -> lat3 = r3@w_out3+b_out3; x=[r2|lat3];
// h1=relu(x@w1+b1); out=h1@w2+b2.  All fp32, weights from L2.
// grid 250 blocks x 256 threads.
// ------------------------------------------------------------------
__global__ __launch_bounds__(256)
void head_kernel(const float* __restrict__ r2, const float* __restrict__ r3,
                 const float* __restrict__ w_out3, const float* __restrict__ b_out3,
                 const float* __restrict__ w1, const float* __restrict__ b1,
                 const float* __restrict__ w2, const float* __restrict__ b2,
                 float* __restrict__ out)
{
  __shared__ float r3_s[8 * 384];
  __shared__ float x_s[8 * 640];
  __shared__ float h1_s[8 * 128];
  int t = threadIdx.x;
  int g0 = blockIdx.x * 8;

  // stage r3 (8x384) and r2 -> x_s[:,0:384]
  for (int idx = t; idx < 8 * 384; idx += 256){
    int gi = idx / 384, c = idx % 384;
    r3_s[idx] = r3[(size_t)(g0 + gi) * 384 + c];
    x_s[gi * 640 + c] = r2[(size_t)(g0 + gi) * 384 + c];
  }
  __syncthreads();

  // lat3: x_s[:,384+c] = b_out3[c] + sum_k r3_s[gi][k]*w_out3[k][c]
  for (int gi = 0; gi < 8; gi++){
    float acc = b_out3[t];
#pragma unroll 4
    for (int k = 0; k < 384; k++) acc += r3_s[gi * 384 + k] * w_out3[k * 256 + t];
    x_s[gi * 640 + 384 + t] = acc;
  }
  __syncthreads();

  // h1 = relu(x @ w1 + b1): 8*128 outputs
#pragma unroll
  for (int i = 0; i < 4; i++){
    int o = i * 256 + t;
    int gi = o >> 7, c = o & 127;
    float acc = b1[c];
#pragma unroll 4
    for (int k = 0; k < 640; k++) acc += x_s[gi * 640 + k] * w1[k * 128 + c];
    h1_s[o] = fmaxf(acc, 0.f);
  }
  __syncthreads();

  // out = h1 @ w2 + b2
#pragma unroll
  for (int i = 0; i < 4; i++){
    int o = i * 256 + t;
    int gi = o >> 7, c = o & 127;
    float acc = b2[c];
#pragma unroll 4
    for (int k = 0; k < 128; k++) acc += h1_s[gi * 128 + k] * w2[k * 128 + c];
    out[(size_t)(g0 + gi) * 128 + c] = acc;
  }
}

// ------------------------------------------------------------------
// bf16 MFMA GEMM, 64x128 tile:
// C/C16 = A[M,K] @ Bt^T (+bias)(+resid). Bt PRE-TRANSPOSED [NC][K] bf16.
// 256 threads = 4 waves; wave owns 16 rows x 128 cols. K-chunk 32.
//  MODE 0: A16 row-major bf16 (lda)
//  MODE 2: k<128 from A16=h16; k>=128 from bf16 agg16 (chunk-local),
//          scaled by amp/att for the 2nd/3rd copies.
// C (fp32) and C16 (bf16) each optional.
// ------------------------------------------------------------------
template<int MODE>
__global__ __launch_bounds__(256)
void mgemm_kernel(const short* __restrict__ A16, int lda,
                  const short* __restrict__ Bt,
                  const float* __restrict__ bias,
                  const float* __restrict__ resid,
                  float* __restrict__ C, short* __restrict__ C16,
                  int M, int K, int NC,
                  const short* __restrict__ agg16,
                  const float* __restrict__ amp,
                  const float* __restrict__ att)
{
  __shared__ short As[64][40];    // [row][k], +8 pad
  __shared__ short Bs[128][40];   // [col][k]

  int tid = threadIdx.x;
  int row0 = blockIdx.y * 64;
  int col0 = blockIdx.x * 128;
  int wv = tid >> 6, ln = tid & 63;
  int lo = ln & 15, q = ln >> 4;

  fx4 acc[8];
#pragma unroll
  for (int ct = 0; ct < 8; ct++) acc[ct] = (fx4){0.f, 0.f, 0.f, 0.f};

  int a_row = tid >> 2;          // 0..63
  int a_ko  = (tid & 3) * 8;     // 0,8,16,24
  int b_col = tid & 127;         // 0..127
  int b_kh  = (tid >> 7) * 16;   // 0 or 16

  for (int k0 = 0; k0 < K; k0 += 32){
    // ---- stage A ----
    {
      int grow = row0 + a_row;
      int gk = k0 + a_ko;
      short8 v = {0,0,0,0,0,0,0,0};
      if (grow < M){
        if (MODE == 0 || gk < 128){
          v = *(const short8*)(A16 + (size_t)grow * lda + gk);
        } else {
          if (gk < 640){
            v = *(const short8*)(agg16 + (size_t)grow * 512 + (gk - 128));
          } else {
            int base; float sc;
            if (gk < 1152){ base = gk - 640;  sc = amp[grow]; }
            else          { base = gk - 1152; sc = att[grow]; }
            short8 tt = *(const short8*)(agg16 + (size_t)grow * 512 + base);
#pragma unroll
            for (int j = 0; j < 8; j++) ((short*)&v)[j] = bf16r(bf16f(((short*)&tt)[j]) * sc);
          }
        }
      }
      *(short8*)&As[a_row][a_ko] = v;
    }
    // ---- stage B ----
    {
      const short* p = Bt + (size_t)(col0 + b_col) * K + k0 + b_kh;
      *(short8*)&Bs[b_col][b_kh]     = *(const short8*)p;
      *(short8*)&Bs[b_col][b_kh + 8] = *(const short8*)(p + 8);
    }
    __syncthreads();
    short8 af = *(const short8*)&As[wv * 16 + lo][q * 8];
#pragma unroll
    for (int ct = 0; ct < 8; ct++){
      short8 bf = *(const short8*)&Bs[ct * 16 + lo][q * 8];
      acc[ct] = __builtin_amdgcn_mfma_f32_16x16x32_bf16(af, bf, acc[ct], 0, 0, 0);
    }
    __syncthreads();
  }

#pragma unroll
  for (int r = 0; r < 4; r++){
    int row = row0 + wv * 16 + q * 4 + r;
    if (row >= M) continue;
#pragma unroll
    for (int ct = 0; ct < 8; ct++){
      int col = col0 + ct * 16 + lo;
      float v = acc[ct][r];
      if (bias)  v += bias[col];
      if (resid) v += resid[(size_t)row * NC + col];
      if (C)   C[(size_t)row * NC + col] = v;
      if (C16) C16[(size_t)row * NC + col] = bf16r(v);
    }
  }
}

// ------------------------------------------------------------------
extern "C" void kernel_launch(void* const* d_in, const int* in_sizes, int n_in,
                              void* d_out, int out_size, void* d_ws, size_t ws_size,
                              hipStream_t stream)
{
  const int*   node_feat = (const int*)  d_in[0];
  const int*   edge_feat = (const int*)  d_in[1];
  const int*   src       = (const int*)  d_in[2];
  const int*   dst       = (const int*)  d_in[3];
  const float* aemb_f  = (const float*) d_in[5];
  const float* bemb_f  = (const float*) d_in[6];
  const float* w_pre_f = (const float*) d_in[7];
  const float* b_pre_f = (const float*) d_in[8];
  const float* w_post_f= (const float*) d_in[9];
  const float* b_post_f= (const float*) d_in[10];
  const float* w_out3  = (const float*) d_in[11];
  const float* b_out3  = (const float*) d_in[12];
  const float* aemb    = (const float*) d_in[13];
  const float* bemb    = (const float*) d_in[14];
  const float* w_pre   = (const float*) d_in[15];
  const float* b_pre   = (const float*) d_in[16];
  const float* w_post  = (const float*) d_in[17];
  const float* b_post  = (const float*) d_in[18];
  const float* w1      = (const float*) d_in[19];
  const float* b1      = (const float*) d_in[20];
  const float* w2      = (const float*) d_in[21];
  const float* b2      = (const float*) d_in[22];
  float* out = (float*)d_out;

  // ---- workspace carve ----
  char* w = (char*)d_ws;
  auto carve = [&](size_t bytes) -> void* {
    void* p = (void*)w;
    w += (bytes + 255) & ~(size_t)255;
    return p;
  };
  float* h_a       = (float*)carve((size_t)Nn * Hc * 4);
  float* h_b       = (float*)carve((size_t)Nn * Hc * 4);
  short* h16_a     = (short*)carve((size_t)Nn * Hc * 2);
  short* h16_b     = (short*)carve((size_t)Nn * Hc * 2);
  short* hsd16     = (short*)carve((size_t)Nn * 256 * 2);
  short* btpre_all = (short*)carve((size_t)2 * Lc * 256 * 128 * 2);
  short* btpost_all= (short*)carve((size_t)2 * Lc * 128 * 1664 * 2);
  float* bsum2     = (float*)carve((size_t)2 * 125 * Hc * 4);
  float* ezt_all   = (float*)carve((size_t)2 * Lc * 125 * Hc * 4);
  float* amp       = (float*)carve((size_t)Nn * 4);
  float* att       = (float*)carve((size_t)Nn * 4);
  float* r3        = (float*)carve((size_t)Gg * 384 * 4);
  float* r2        = (float*)carve((size_t)Gg * 384 * 4);
  int* deg      = (int*)carve((size_t)Nn * 4);
  int* rowstart = (int*)carve((size_t)(Nn + 1) * 4);
  int* cursor   = (int*)carve((size_t)Nn * 4);
  int* part     = (int*)carve((size_t)50176 * 4);
  int* bsums    = (int*)carve((size_t)64 * 4);
  int* src_srt  = (int*)carve((size_t)Ee * 4);
  int* code_srt = (int*)carve((size_t)Ee * 4);

  size_t fixed_bytes = (size_t)(w - (char*)d_ws);
  size_t avail = (ws_size > fixed_bytes) ? (ws_size - fixed_bytes) : 0;
  long max_rows = (long)(avail / (512 * 2));
  int chunk = (max_rows >= Nn) ? Nn : (int)(max_rows & ~127L);
  if (chunk < 128) chunk = 128;
  short* agg16 = (short*)w;   // chunk * 512 bf16

  // ---- graph preprocessing ----
  hipMemsetAsync(deg, 0, (size_t)Nn * 4, stream);
  deg_kernel<<<(Ee + 255) / 256, 256, 0, stream>>>(dst, deg, Ee);
  scan1_kernel<<<49, 1024, 0, stream>>>(deg, part, bsums, Nn);
  scan2_kernel<<<1, 64, 0, stream>>>(bsums, 49);
  scan3_kernel<<<(Nn + 255) / 256, 256, 0, stream>>>(part, bsums, rowstart, Nn);
  copy_int_kernel<<<(Nn + 255) / 256, 256, 0, stream>>>(rowstart, cursor, Nn);
  scatter_kernel<<<(Ee + 255) / 256, 256, 0, stream>>>(src, dst, edge_feat, cursor,
                                                       src_srt, code_srt, Ee);
  ampatt_kernel<<<(Nn + 255) / 256, 256, 0, stream>>>(deg, amp, att, Nn);

  // ---- up-front shared tables (both branches) ----
  bsum2_kernel<<<(2 * 125 * Hc + 255) / 256, 256, 0, stream>>>(bemb_f, bemb, bsum2);
  conv_pre_all_kernel<<<(2 * Lc * 256 * 128 + 255) / 256, 256, 0, stream>>>(
      w_pre_f, w_pre, btpre_all);
  conv_post_all_kernel<<<(2 * Lc * 1664 * 128 + 255) / 256, 256, 0, stream>>>(
      w_post_f, w_post, btpost_all);
  ezt_all_kernel<<<dim3(125, 2 * Lc), 128, 0, stream>>>(
      w_pre_f, w_pre, b_pre_f, b_pre, bsum2, ezt_all);

  // ---- one PNA branch ----
  auto run_branch = [&](int bidx, const float* aemb_p,
                        const float* b_post_p, float* r_out)
  {
    float* h_cur = h_a;   float* h_nxt = h_b;
    short* g_cur = h16_a; short* g_nxt = h16_b;
    embed_node_kernel<<<(Nn * Hc + 255) / 256, 256, 0, stream>>>(node_feat, aemb_p, h_cur, g_cur);
    for (int l = 0; l < Lc; l++){
      int bl = bidx * Lc + l;
      // hsd16 = h16 @ [W_src|W_dst]  (bf16 out)
      mgemm_kernel<0><<<dim3(2, (Nn + 63) / 64), 256, 0, stream>>>(
          g_cur, 128, btpre_all + (size_t)bl * 256 * 128, nullptr, nullptr,
          nullptr, hsd16, Nn, 128, 256, nullptr, nullptr, nullptr);
      const float* ezt_l = ezt_all + (size_t)bl * 125 * Hc;
      for (int n0 = 0; n0 < Nn; n0 += chunk){
        int rows = (Nn - n0 < chunk) ? (Nn - n0) : chunk;
        agg_kernel<<<rows, 128, 0, stream>>>(hsd16, ezt_l, src_srt, code_srt,
                                             rowstart, agg16, n0);
        mgemm_kernel<2><<<dim3(1, (rows + 63) / 64), 256, 0, stream>>>(
            g_cur + (size_t)n0 * Hc, 128, btpost_all + (size_t)bl * 128 * 1664,
            b_post_p + (size_t)l * 128,
            h_cur + (size_t)n0 * Hc,
            h_nxt + (size_t)n0 * Hc, g_nxt + (size_t)n0 * Hc,
            rows, 1664, 128, agg16, amp + n0, att + n0);
      }
      { float* t = h_cur; h_cur = h_nxt; h_nxt = t; }
      { short* t = g_cur; g_cur = g_nxt; g_nxt = t; }
    }
    readout_kernel<<<Gg, 128, 0, stream>>>(h_cur, r_out);
  };

  run_branch(0, aemb_f, b_post_f, r3);   // frozen 3D branch
  run_branch(1, aemb,   b_post,   r2);   // trainable 2D branch

  // fused head: lat3 + concat + MLP
  head_kernel<<<Gg / 8, 256, 0, stream>>>(r2, r3, w_out3, b_out3, w1, b1, w2, b2, out);
}

// Round 6
// 1704.638 us; speedup vs baseline: 3.9207x; 1.2007x over previous
//
#include <hip/hip_runtime.h>
#include <hip/hip_bf16.h>
#include <math.h>

// Problem constants (fixed by the reference)
#define Nn 50000
#define Ee 400000
#define Gg 2000
#define NPGc 25
#define Hc 128
#define Lc 5

typedef __attribute__((ext_vector_type(8))) short short8;   // 8 bf16 = 4 VGPRs
typedef __attribute__((ext_vector_type(4))) float fx4;      // MFMA accumulator

__device__ inline short bf16r(float x){
  unsigned u = __float_as_uint(x);
  unsigned r = (u + 0x7fffu + ((u >> 16) & 1u)) >> 16;
  return (short)r;
}
__device__ inline float bf16f(short s){
  return __uint_as_float(((unsigned)(unsigned short)s) << 16);
}

// ------------------------------------------------------------------
// Graph preprocessing
// ------------------------------------------------------------------
__global__ void deg_kernel(const int* __restrict__ dst, int* __restrict__ deg, int E){
  int i = blockIdx.x * blockDim.x + threadIdx.x;
  if (i < E) atomicAdd(&deg[dst[i]], 1);
}

// 3-phase parallel scan
__global__ void scan1_kernel(const int* __restrict__ deg, int* __restrict__ part,
                             int* __restrict__ bsums, int n){
  __shared__ int tmp[1024];
  int b = blockIdx.x, t = threadIdx.x;
  int i = b * 1024 + t;
  int v = (i < n) ? deg[i] : 0;
  tmp[t] = v;
  __syncthreads();
  for (int off = 1; off < 1024; off <<= 1){
    int add = (t >= off) ? tmp[t - off] : 0;
    __syncthreads();
    tmp[t] += add;
    __syncthreads();
  }
  part[i] = tmp[t];
  if (t == 1023) bsums[b] = tmp[1023];
}
__global__ void scan2_kernel(int* __restrict__ bsums, int nb){
  if (threadIdx.x == 0){
    int s = 0;
    for (int i = 0; i < nb; i++){ s += bsums[i]; bsums[i] = s; }
  }
}
__global__ void scan3_kernel(const int* __restrict__ part, const int* __restrict__ bsums,
                             int* __restrict__ rowstart, int n){
  int i = blockIdx.x * blockDim.x + threadIdx.x;
  if (i == 0) rowstart[0] = 0;
  if (i < n){
    int b = i >> 10;
    int base = b ? bsums[b - 1] : 0;
    rowstart[i + 1] = part[i] + base;
  }
}

__global__ void copy_int_kernel(const int* __restrict__ a, int* __restrict__ b, int n){
  int i = blockIdx.x * blockDim.x + threadIdx.x;
  if (i < n) b[i] = a[i];
}

__global__ void scatter_kernel(const int* __restrict__ src, const int* __restrict__ dst,
                               const int* __restrict__ ef, int* cursor,
                               int* __restrict__ src_srt, int* __restrict__ code_srt, int E){
  int i = blockIdx.x * blockDim.x + threadIdx.x;
  if (i >= E) return;
  int p = atomicAdd(&cursor[dst[i]], 1);
  src_srt[p] = src[i];
  code_srt[p] = ef[i * 3 + 0] * 25 + ef[i * 3 + 1] * 5 + ef[i * 3 + 2];
}

__global__ void ampatt_kernel(const int* __restrict__ deg, float* __restrict__ amp,
                              float* __restrict__ att, int n){
  int i = blockIdx.x * blockDim.x + threadIdx.x;
  if (i >= n) return;
  float d = (float)deg[i];
  float ld = logf(d + 1.0f);
  amp[i] = ld;
  att[i] = (deg[i] > 0) ? (1.0f / ld) : 0.0f;
}

// ------------------------------------------------------------------
// Node embedding: h fp32 + bf16 shadow
// ------------------------------------------------------------------
__global__ void embed_node_kernel(const int* __restrict__ nf, const float* __restrict__ aemb,
                                  float* __restrict__ h, short* __restrict__ h16){
  int idx = blockIdx.x * blockDim.x + threadIdx.x;
  if (idx >= Nn * Hc) return;
  int n = idx >> 7, c = idx & 127;
  float s = 0.f;
#pragma unroll
  for (int f = 0; f < 9; f++){
    int row = nf[n * 9 + f] + 16 * f;
    s += aemb[row * Hc + c];
  }
  h[idx] = s;
  h16[idx] = bf16r(s);
}

// bsum2[b][code][c]: 125 distinct edge embeddings, both branches
__global__ void bsum2_kernel(const float* __restrict__ bemb_f, const float* __restrict__ bemb_t,
                             float* __restrict__ bsum2){
  int idx = blockIdx.x * blockDim.x + threadIdx.x;
  if (idx >= 2 * 125 * Hc) return;
  int b = idx / (125 * Hc);
  int rem = idx % (125 * Hc);
  int code = rem >> 7, c = rem & 127;
  int e0 = code / 25, e1 = (code / 5) % 5, e2 = code % 5;
  const float* bemb = b ? bemb_t : bemb_f;
  bsum2[idx] = bemb[e0 * Hc + c] + bemb[(5 + e1) * Hc + c] + bemb[(10 + e2) * Hc + c];
}

// ------------------------------------------------------------------
// up-front weight converts, both branches x 5 layers
// ------------------------------------------------------------------
__global__ void conv_pre_all_kernel(const float* __restrict__ wpre_f,
                                    const float* __restrict__ wpre_t,
                                    short* __restrict__ btpre_all){
  int idx = blockIdx.x * blockDim.x + threadIdx.x;
  if (idx >= 2 * Lc * 256 * 128) return;
  int bl = idx / (256 * 128);
  int rem = idx % (256 * 128);
  int col = rem >> 7, k = rem & 127;
  int b = bl / Lc, l = bl % Lc;
  const float* wl = (b ? wpre_t : wpre_f) + (size_t)l * 384 * 128;
  float v = (col < 128) ? wl[k * 128 + col] : wl[(128 + k) * 128 + (col - 128)];
  btpre_all[(size_t)bl * 256 * 128 + col * 128 + k] = bf16r(v);
}
__global__ void conv_post_all_kernel(const float* __restrict__ wpost_f,
                                     const float* __restrict__ wpost_t,
                                     short* __restrict__ btpost_all){
  int idx = blockIdx.x * blockDim.x + threadIdx.x;
  if (idx >= 2 * Lc * 1664 * 128) return;
  int bl = idx / (1664 * 128);
  int rem = idx % (1664 * 128);
  int k = rem >> 7, c = rem & 127;
  int b = bl / Lc, l = bl % Lc;
  const float* wl = (b ? wpost_t : wpost_f) + (size_t)l * 1664 * 128;
  btpost_all[(size_t)bl * 128 * 1664 + (size_t)c * 1664 + k] = bf16r(wl[(size_t)k * 128 + c]);
}

// ezt_all[bl][code][c] = bsum2[b][code][:] @ W_e[b,l] + b_pre[b,l]
__global__ void ezt_all_kernel(const float* __restrict__ wpre_f, const float* __restrict__ wpre_t,
                               const float* __restrict__ bpre_f, const float* __restrict__ bpre_t,
                               const float* __restrict__ bsum2, float* __restrict__ ezt_all){
  int code = blockIdx.x;
  int bl   = blockIdx.y;
  int t = threadIdx.x;
  int b = bl / Lc, l = bl % Lc;
  const float* wl = (b ? wpre_t : wpre_f) + (size_t)l * 384 * 128 + 256 * 128;
  const float* bp = (b ? bpre_t : bpre_f) + (size_t)l * 128;
  __shared__ float bs[128];
  bs[t] = bsum2[((size_t)b * 125 + code) * 128 + t];
  __syncthreads();
  float acc = bp[t];
#pragma unroll 8
  for (int k = 0; k < 128; k++) acc += bs[k] * wl[k * 128 + t];
  ezt_all[((size_t)bl * 125 + code) * 128 + t] = acc;
}

// ------------------------------------------------------------------
// PNA aggregation, 1 wave/block, 2 channels per lane (int-packed bf16)
// hsdP = (int*)hsd16: [N][128] ints, ints 0..63 = hs pairs, 64..127 = hd
// aggP = (int*)agg16: [chunkrow][256] ints = mean|max|min|std pairs
// ------------------------------------------------------------------
__global__ void agg_kernel(const int* __restrict__ hsdP, const float* __restrict__ ezt,
                           const int* __restrict__ src_srt, const int* __restrict__ code_srt,
                           const int* __restrict__ rowstart,
                           int* __restrict__ aggP, int n0){
  int n = n0 + blockIdx.x;
  int c2 = threadIdx.x;     // 0..63 -> channels 2*c2, 2*c2+1
  int s0 = rowstart[n], s1 = rowstart[n + 1];
  int* outp = aggP + (size_t)blockIdx.x * 256;
  if (s1 == s0){
    outp[c2] = 0; outp[64 + c2] = 0; outp[128 + c2] = 0; outp[192 + c2] = 0;
    return;
  }
  int hdp = hsdP[(size_t)n * 128 + 64 + c2];
  float hd0 = bf16f((short)(hdp & 0xffff));
  float hd1 = bf16f((short)(((unsigned)hdp) >> 16));
  float sum0 = 0.f, sum1 = 0.f, sq0 = 0.f, sq1 = 0.f;
  float mx0 = -3.402823466e38f, mx1 = -3.402823466e38f;
  float mn0 = 3.402823466e38f,  mn1 = 3.402823466e38f;
  for (int k = s0; k < s1; k++){
    int sidx = src_srt[k];
    int hp = hsdP[(size_t)sidx * 128 + c2];
    float2 ez = *(const float2*)(ezt + (size_t)code_srt[k] * 128 + 2 * c2);
    float z0 = bf16f((short)(hp & 0xffff)) + hd0 + ez.x;
    float z1 = bf16f((short)(((unsigned)hp) >> 16)) + hd1 + ez.y;
    sum0 += z0; sum1 += z1;
    sq0 += z0 * z0; sq1 += z1 * z1;
    mx0 = fmaxf(mx0, z0); mx1 = fmaxf(mx1, z1);
    mn0 = fminf(mn0, z0); mn1 = fminf(mn1, z1);
  }
  float d = (float)(s1 - s0);
  float m0 = sum0 / d, m1 = sum1 / d;
  float v0 = sq0 / d - m0 * m0; v0 = v0 > 0.f ? v0 : 0.f;
  float v1 = sq1 / d - m1 * m1; v1 = v1 > 0.f ? v1 : 0.f;
  float sd0 = sqrtf(v0 + 1e-5f), sd1 = sqrtf(v1 + 1e-5f);
  auto pack = [](float a, float b) -> int {
    return (int)(((unsigned)(unsigned short)bf16r(a)) |
                 (((unsigned)(unsigned short)bf16r(b)) << 16));
  };
  outp[c2]        = pack(m0, m1);
  outp[64 + c2]   = pack(mx0, mx1);
  outp[128 + c2]  = pack(mn0, mn1);
  outp[192 + c2]  = pack(sd0, sd1);
}

// ------------------------------------------------------------------
// Graph readout: [min | max | mean]
// ------------------------------------------------------------------
__global__ void readout_kernel(const float* __restrict__ h, float* __restrict__ r){
  int g = blockIdx.x, c = threadIdx.x;
  float mn = 3.402823466e38f, mx = -3.402823466e38f, s = 0.f;
  const float* hp = h + (size_t)g * NPGc * Hc + c;
#pragma unroll
  for (int i = 0; i < NPGc; i++){
    float v = hp[i * Hc];
    mn = fminf(mn, v); mx = fmaxf(mx, v); s += v;
  }
  r[(size_t)g * 384 + c]       = mn;
  r[(size_t)g * 384 + 128 + c] = mx;
  r[(size_t)g * 384 + 256 + c] = s * (1.0f / NPGc);
}

// ------------------------------------------------------------------
// Fused head, ONE GRAPH PER BLOCK (2000 blocks, weights L2-hot):
// lat3 = r3@w_out3+b_out3; x=[r2|lat3]; h1=relu(x@w1+b1); out=h1@w2+b2
// ------------------------------------------------------------------
__global__ __launch_bounds__(256)
void head_kernel(const float* __restrict__ r2, const float* __restrict__ r3,
                 const float* __restrict__ w_out3, const float* __restrict__ b_out3,
                 const float* __restrict__ w1, const float* __restrict__ b1,
                 const float* __restrict__ w2, const float* __restrict__ b2,
                 float* __restrict__ out)
{
  __shared__ float r3_s[384];
  __shared__ float x_s[640];
  __shared__ float h1_s[128];
  __shared__ float partial[256];
  int g = blockIdx.x, t = threadIdx.x;

  for (int i = t; i < 384; i += 256){
    float v2 = r2[(size_t)g * 384 + i];
    r3_s[i] = r3[(size_t)g * 384 + i];
    x_s[i] = v2;
  }
  __syncthreads();

  // lat3: 256 cols, one per thread
  {
    float acc = b_out3[t];
#pragma unroll 8
    for (int k = 0; k < 384; k++) acc += r3_s[k] * w_out3[k * 256 + t];
    x_s[384 + t] = acc;
  }
  __syncthreads();

  // h1 = relu(x @ w1 + b1): 128 cols, split K across 2 half-waves
  {
    int c = t & 127, half = t >> 7;
    float acc = half ? 0.f : b1[c];
    int kb = half * 320;
#pragma unroll 8
    for (int k = kb; k < kb + 320; k++) acc += x_s[k] * w1[k * 128 + c];
    partial[t] = acc;
  }
  __syncthreads();
  if (t < 128) h1_s[t] = fmaxf(partial[t] + partial[t + 128], 0.f);
  __syncthreads();

  // out = h1 @ w2 + b2: 128 cols, split K
  {
    int c = t & 127, half = t >> 7;
    float acc = half ? 0.f : b2[c];
    int kb = half * 64;
#pragma unroll 8
    for (int k = kb; k < kb + 64; k++) acc += h1_s[k] * w2[k * 128 + c];
    partial[t] = acc;
  }
  __syncthreads();
  if (t < 128) out[(size_t)g * 128 + t] = partial[t] + partial[t + 128];
}

// ------------------------------------------------------------------
// bf16 MFMA GEMM, 64x128 tile, K-chunk 64 (half the barriers):
// C/C16 = A[M,K] @ Bt^T (+bias)(+resid). Bt PRE-TRANSPOSED [NC][K] bf16.
//  MODE 0: A16 row-major bf16 (lda)
//  MODE 2: k<128 from A16=h16; k>=128 from bf16 agg16 (chunk-local),
//          scaled by amp/att for the 2nd/3rd copies.
// K % 64 == 0. Segment boundaries (128,640,1152) are 16-aligned, and A
// staging windows are 16-wide 16-aligned, so no window straddles.
// ------------------------------------------------------------------
template<int MODE>
__global__ __launch_bounds__(256)
void mgemm_kernel(const short* __restrict__ A16, int lda,
                  const short* __restrict__ Bt,
                  const float* __restrict__ bias,
                  const float* __restrict__ resid,
                  float* __restrict__ C, short* __restrict__ C16,
                  int M, int K, int NC,
                  const short* __restrict__ agg16,
                  const float* __restrict__ amp,
                  const float* __restrict__ att)
{
  __shared__ short As[64][72];    // [row][k], +8 pad
  __shared__ short Bs[128][72];   // [col][k]

  int tid = threadIdx.x;
  int row0 = blockIdx.y * 64;
  int col0 = blockIdx.x * 128;
  int wv = tid >> 6, ln = tid & 63;
  int lo = ln & 15, q = ln >> 4;

  fx4 acc[8];
#pragma unroll
  for (int ct = 0; ct < 8; ct++) acc[ct] = (fx4){0.f, 0.f, 0.f, 0.f};

  int a_row = tid >> 2;          // 0..63
  int a_ko  = (tid & 3) * 16;    // 0,16,32,48
  int b_col = tid & 127;         // 0..127
  int b_kh  = (tid >> 7) * 32;   // 0 or 32

  for (int k0 = 0; k0 < K; k0 += 64){
    // ---- stage A: 16 shorts (two short8) per thread ----
    {
      int grow = row0 + a_row;
      int gk = k0 + a_ko;
      short8 v0 = {0,0,0,0,0,0,0,0}, v1 = {0,0,0,0,0,0,0,0};
      if (grow < M){
        if (MODE == 0 || gk < 128){
          const short* p = A16 + (size_t)grow * lda + gk;
          v0 = *(const short8*)p;
          v1 = *(const short8*)(p + 8);
        } else {
          int base; float sc; bool scaled;
          if (gk < 640)      { base = gk - 128;  sc = 1.f; scaled = false; }
          else if (gk < 1152){ base = gk - 640;  sc = amp[grow]; scaled = true; }
          else               { base = gk - 1152; sc = att[grow]; scaled = true; }
          const short* p = agg16 + (size_t)grow * 512 + base;
          v0 = *(const short8*)p;
          v1 = *(const short8*)(p + 8);
          if (scaled){
#pragma unroll
            for (int j = 0; j < 8; j++) ((short*)&v0)[j] = bf16r(bf16f(((short*)&v0)[j]) * sc);
#pragma unroll
            for (int j = 0; j < 8; j++) ((short*)&v1)[j] = bf16r(bf16f(((short*)&v1)[j]) * sc);
          }
        }
      }
      *(short8*)&As[a_row][a_ko]     = v0;
      *(short8*)&As[a_row][a_ko + 8] = v1;
    }
    // ---- stage B: 32 shorts (four short8) per thread ----
    {
      const short* p = Bt + (size_t)(col0 + b_col) * K + k0 + b_kh;
      *(short8*)&Bs[b_col][b_kh]      = *(const short8*)p;
      *(short8*)&Bs[b_col][b_kh + 8]  = *(const short8*)(p + 8);
      *(short8*)&Bs[b_col][b_kh + 16] = *(const short8*)(p + 16);
      *(short8*)&Bs[b_col][b_kh + 24] = *(const short8*)(p + 24);
    }
    __syncthreads();
    short8 af0 = *(const short8*)&As[wv * 16 + lo][q * 8];
    short8 af1 = *(const short8*)&As[wv * 16 + lo][32 + q * 8];
#pragma unroll
    for (int ct = 0; ct < 8; ct++){
      short8 bf0 = *(const short8*)&Bs[ct * 16 + lo][q * 8];
      short8 bf1 = *(const short8*)&Bs[ct * 16 + lo][32 + q * 8];
      acc[ct] = __builtin_amdgcn_mfma_f32_16x16x32_bf16(af0, bf0, acc[ct], 0, 0, 0);
      acc[ct] = __builtin_amdgcn_mfma_f32_16x16x32_bf16(af1, bf1, acc[ct], 0, 0, 0);
    }
    __syncthreads();
  }

#pragma unroll
  for (int r = 0; r < 4; r++){
    int row = row0 + wv * 16 + q * 4 + r;
    if (row >= M) continue;
#pragma unroll
    for (int ct = 0; ct < 8; ct++){
      int col = col0 + ct * 16 + lo;
      float v = acc[ct][r];
      if (bias)  v += bias[col];
      if (resid) v += resid[(size_t)row * NC + col];
      if (C)   C[(size_t)row * NC + col] = v;
      if (C16) C16[(size_t)row * NC + col] = bf16r(v);
    }
  }
}

// ------------------------------------------------------------------
extern "C" void kernel_launch(void* const* d_in, const int* in_sizes, int n_in,
                              void* d_out, int out_size, void* d_ws, size_t ws_size,
                              hipStream_t stream)
{
  const int*   node_feat = (const int*)  d_in[0];
  const int*   edge_feat = (const int*)  d_in[1];
  const int*   src       = (const int*)  d_in[2];
  const int*   dst       = (const int*)  d_in[3];
  const float* aemb_f  = (const float*) d_in[5];
  const float* bemb_f  = (const float*) d_in[6];
  const float* w_pre_f = (const float*) d_in[7];
  const float* b_pre_f = (const float*) d_in[8];
  const float* w_post_f= (const float*) d_in[9];
  const float* b_post_f= (const float*) d_in[10];
  const float* w_out3  = (const float*) d_in[11];
  const float* b_out3  = (const float*) d_in[12];
  const float* aemb    = (const float*) d_in[13];
  const float* bemb    = (const float*) d_in[14];
  const float* w_pre   = (const float*) d_in[15];
  const float* b_pre   = (const float*) d_in[16];
  const float* w_post  = (const float*) d_in[17];
  const float* b_post  = (const float*) d_in[18];
  const float* w1      = (const float*) d_in[19];
  const float* b1      = (const float*) d_in[20];
  const float* w2      = (const float*) d_in[21];
  const float* b2      = (const float*) d_in[22];
  float* out = (float*)d_out;

  // ---- workspace carve ----
  char* w = (char*)d_ws;
  auto carve = [&](size_t bytes) -> void* {
    void* p = (void*)w;
    w += (bytes + 255) & ~(size_t)255;
    return p;
  };
  float* h_a       = (float*)carve((size_t)Nn * Hc * 4);
  float* h_b       = (float*)carve((size_t)Nn * Hc * 4);
  short* h16_a     = (short*)carve((size_t)Nn * Hc * 2);
  short* h16_b     = (short*)carve((size_t)Nn * Hc * 2);
  short* hsd16     = (short*)carve((size_t)Nn * 256 * 2);
  short* btpre_all = (short*)carve((size_t)2 * Lc * 256 * 128 * 2);
  short* btpost_all= (short*)carve((size_t)2 * Lc * 128 * 1664 * 2);
  float* bsum2     = (float*)carve((size_t)2 * 125 * Hc * 4);
  float* ezt_all   = (float*)carve((size_t)2 * Lc * 125 * Hc * 4);
  float* amp       = (float*)carve((size_t)Nn * 4);
  float* att       = (float*)carve((size_t)Nn * 4);
  float* r3        = (float*)carve((size_t)Gg * 384 * 4);
  float* r2        = (float*)carve((size_t)Gg * 384 * 4);
  int* deg      = (int*)carve((size_t)Nn * 4);
  int* rowstart = (int*)carve((size_t)(Nn + 1) * 4);
  int* cursor   = (int*)carve((size_t)Nn * 4);
  int* part     = (int*)carve((size_t)50176 * 4);
  int* bsums    = (int*)carve((size_t)64 * 4);
  int* src_srt  = (int*)carve((size_t)Ee * 4);
  int* code_srt = (int*)carve((size_t)Ee * 4);

  size_t fixed_bytes = (size_t)(w - (char*)d_ws);
  size_t avail = (ws_size > fixed_bytes) ? (ws_size - fixed_bytes) : 0;
  long max_rows = (long)(avail / (512 * 2));
  int chunk = (max_rows >= Nn) ? Nn : (int)(max_rows & ~127L);
  if (chunk < 128) chunk = 128;
  short* agg16 = (short*)w;   // chunk * 512 bf16

  // ---- graph preprocessing ----
  hipMemsetAsync(deg, 0, (size_t)Nn * 4, stream);
  deg_kernel<<<(Ee + 255) / 256, 256, 0, stream>>>(dst, deg, Ee);
  scan1_kernel<<<49, 1024, 0, stream>>>(deg, part, bsums, Nn);
  scan2_kernel<<<1, 64, 0, stream>>>(bsums, 49);
  scan3_kernel<<<(Nn + 255) / 256, 256, 0, stream>>>(part, bsums, rowstart, Nn);
  copy_int_kernel<<<(Nn + 255) / 256, 256, 0, stream>>>(rowstart, cursor, Nn);
  scatter_kernel<<<(Ee + 255) / 256, 256, 0, stream>>>(src, dst, edge_feat, cursor,
                                                       src_srt, code_srt, Ee);
  ampatt_kernel<<<(Nn + 255) / 256, 256, 0, stream>>>(deg, amp, att, Nn);

  // ---- up-front shared tables ----
  bsum2_kernel<<<(2 * 125 * Hc + 255) / 256, 256, 0, stream>>>(bemb_f, bemb, bsum2);
  conv_pre_all_kernel<<<(2 * Lc * 256 * 128 + 255) / 256, 256, 0, stream>>>(
      w_pre_f, w_pre, btpre_all);
  conv_post_all_kernel<<<(2 * Lc * 1664 * 128 + 255) / 256, 256, 0, stream>>>(
      w_post_f, w_post, btpost_all);
  ezt_all_kernel<<<dim3(125, 2 * Lc), 128, 0, stream>>>(
      w_pre_f, w_pre, b_pre_f, b_pre, bsum2, ezt_all);

  // ---- one PNA branch ----
  auto run_branch = [&](int bidx, const float* aemb_p,
                        const float* b_post_p, float* r_out)
  {
    float* h_cur = h_a;   float* h_nxt = h_b;
    short* g_cur = h16_a; short* g_nxt = h16_b;
    embed_node_kernel<<<(Nn * Hc + 255) / 256, 256, 0, stream>>>(node_feat, aemb_p, h_cur, g_cur);
    for (int l = 0; l < Lc; l++){
      int bl = bidx * Lc + l;
      // hsd16 = h16 @ [W_src|W_dst]  (bf16 out)
      mgemm_kernel<0><<<dim3(2, (Nn + 63) / 64), 256, 0, stream>>>(
          g_cur, 128, btpre_all + (size_t)bl * 256 * 128, nullptr, nullptr,
          nullptr, hsd16, Nn, 128, 256, nullptr, nullptr, nullptr);
      const float* ezt_l = ezt_all + (size_t)bl * 125 * Hc;
      for (int n0 = 0; n0 < Nn; n0 += chunk){
        int rows = (Nn - n0 < chunk) ? (Nn - n0) : chunk;
        agg_kernel<<<rows, 64, 0, stream>>>((const int*)hsd16, ezt_l, src_srt, code_srt,
                                            rowstart, (int*)agg16, n0);
        mgemm_kernel<2><<<dim3(1, (rows + 63) / 64), 256, 0, stream>>>(
            g_cur + (size_t)n0 * Hc, 128, btpost_all + (size_t)bl * 128 * 1664,
            b_post_p + (size_t)l * 128,
            h_cur + (size_t)n0 * Hc,
            h_nxt + (size_t)n0 * Hc, g_nxt + (size_t)n0 * Hc,
            rows, 1664, 128, agg16, amp + n0, att + n0);
      }
      { float* t = h_cur; h_cur = h_nxt; h_nxt = t; }
      { short* t = g_cur; g_cur = g_nxt; g_nxt = t; }
    }
    readout_kernel<<<Gg, 128, 0, stream>>>(h_cur, r_out);
  };

  run_branch(0, aemb_f, b_post_f, r3);   // frozen 3D branch
  run_branch(1, aemb,   b_post,   r2);   // trainable 2D branch

  head_kernel<<<Gg, 256, 0, stream>>>(r2, r3, w_out3, b_out3, w1, b1, w2, b2, out);
}